// Round 5
// baseline (1841.267 us; speedup 1.0000x reference)
//
#include <hip/hip_runtime.h>
#include <hip/hip_bf16.h>
#include <stdint.h>

// Sizes (fixed for this problem)
#define B_ 2
#define T_ 2048
#define H_ 1024
#define M_ 4096            // B*T
#define DI 2048
#define DS 128
#define CONVD 2304         // DI + 2*DS
#define LD2 4480           // in_proj out cols: 4384 padded to 128-multiple
#define EPS_ 1e-6f

typedef __bf16 bf16x8 __attribute__((ext_vector_type(8)));
typedef float f32x4 __attribute__((ext_vector_type(4)));
typedef uint32_t u32x4 __attribute__((ext_vector_type(4)));

__device__ __forceinline__ unsigned short f2bfu(float f) {
    union { float f; uint32_t u; } a; a.f = f;
    uint32_t r = a.u + 0x7FFFu + ((a.u >> 16) & 1u);
    return (unsigned short)(r >> 16);
}
__device__ __forceinline__ float bfu2f(unsigned short u) {
    union { uint32_t u; float f; } a; a.u = ((uint32_t)u) << 16; return a.f;
}
__device__ __forceinline__ float siluf(float x) { return x / (1.f + expf(-x)); }
__device__ __forceinline__ bf16x8 zero8() { bf16x8 r{}; return r; }

// ---------------- RMS over 1024 cols -> bf16 ----------------
__global__ __launch_bounds__(256) void k_rms1024(const float* __restrict__ in, const float* __restrict__ w,
                                                 unsigned short* __restrict__ out) {
    __shared__ float red[4];
    int m = blockIdx.x, tid = threadIdx.x;
    size_t base = (size_t)m * H_ + tid * 4;
    float4 v = *(const float4*)(in + base);
    float ss = v.x * v.x + v.y * v.y + v.z * v.z + v.w * v.w;
#pragma unroll
    for (int off = 32; off; off >>= 1) ss += __shfl_xor(ss, off);
    if ((tid & 63) == 0) red[tid >> 6] = ss;
    __syncthreads();
    float scale = rsqrtf((red[0] + red[1] + red[2] + red[3]) * (1.f / 1024.f) + EPS_);
    float4 wv = *(const float4*)(w + tid * 4);
    ushort4 o;
    o.x = f2bfu(v.x * wv.x * scale); o.y = f2bfu(v.y * wv.y * scale);
    o.z = f2bfu(v.z * wv.z * scale); o.w = f2bfu(v.w * wv.w * scale);
    *(ushort4*)(out + base) = o;
}

// ---------------- transpose fp32 [K,N] -> bf16 [NP,K] (pad rows with 0) ----------------
__global__ __launch_bounds__(256) void k_transpose(const float* __restrict__ src, unsigned short* __restrict__ dst,
                                                   int K, int N, int NP) {
    __shared__ float t[32][33];
    int n0 = blockIdx.x * 32, k0 = blockIdx.y * 32;
    int tx = threadIdx.x & 31, ty = threadIdx.x >> 5;
#pragma unroll
    for (int i = ty; i < 32; i += 8) {
        int k = k0 + i, n = n0 + tx;
        t[i][tx] = (n < N) ? src[(size_t)k * N + n] : 0.f;
    }
    __syncthreads();
#pragma unroll
    for (int i = ty; i < 32; i += 8) {
        int n = n0 + i, k = k0 + tx;
        if (n < NP) dst[(size_t)n * K + k] = f2bfu(t[tx][i]);
    }
}

// ---------------- bf16 MFMA GEMM: C[M,N] = A[M,K] * Bt[N,K]^T, templated epilogue ----------
// EPI: 0 = f32 store, 4 = gelu->bf16, 5 = f32 store of (v + aux) [residual fusion]
template <int EPI>
__global__ __launch_bounds__(256) void k_gemm(const unsigned short* __restrict__ A, const unsigned short* __restrict__ Bt,
                                              void* __restrict__ Cout, const float* __restrict__ aux,
                                              int M, int N, int K) {
    __shared__ alignas(16) unsigned short As[128 * 64];
    __shared__ alignas(16) unsigned short Bs[128 * 64];
    const int tid = threadIdx.x;
    const int m0 = blockIdx.y * 128, n0 = blockIdx.x * 128;
    const int wave = tid >> 6, lane = tid & 63;
    const int wm = (wave >> 1) * 64, wn = (wave & 1) * 64;
    const int fr = lane & 15, fg = lane >> 4;
    const int srow = tid >> 3;
    const int ske = (tid & 7) * 8;

    f32x4 acc[4][4];
#pragma unroll
    for (int m = 0; m < 4; m++)
#pragma unroll
        for (int n = 0; n < 4; n++) acc[m][n] = (f32x4)(0.f);

    const int nk = K >> 6;
    u32x4 ra[4], rb[4];
#pragma unroll
    for (int i = 0; i < 4; i++) {
        ra[i] = *(const u32x4*)(A + (size_t)(m0 + srow + 32 * i) * K + ske);
        rb[i] = *(const u32x4*)(Bt + (size_t)(n0 + srow + 32 * i) * K + ske);
    }
    for (int kt = 0; kt < nk; ++kt) {
        __syncthreads();
#pragma unroll
        for (int i = 0; i < 4; i++) {
            int lin = (tid + 256 * i) * 16;
            int sw = lin ^ (((lin >> 7) & 7) << 4);
            *(u32x4*)((char*)As + sw) = ra[i];
            *(u32x4*)((char*)Bs + sw) = rb[i];
        }
        __syncthreads();
        if (kt + 1 < nk) {
#pragma unroll
            for (int i = 0; i < 4; i++) {
                ra[i] = *(const u32x4*)(A + (size_t)(m0 + srow + 32 * i) * K + (kt + 1) * 64 + ske);
                rb[i] = *(const u32x4*)(Bt + (size_t)(n0 + srow + 32 * i) * K + (kt + 1) * 64 + ske);
            }
        }
#pragma unroll
        for (int ks = 0; ks < 2; ++ks) {
            bf16x8 af[4], bg[4];
#pragma unroll
            for (int m = 0; m < 4; m++) {
                int row = wm + m * 16 + fr;
                int lin = row * 128 + ks * 64 + fg * 16;
                af[m] = *(const bf16x8*)((const char*)As + (lin ^ ((row & 7) << 4)));
            }
#pragma unroll
            for (int n = 0; n < 4; n++) {
                int col = wn + n * 16 + fr;
                int lin = col * 128 + ks * 64 + fg * 16;
                bg[n] = *(const bf16x8*)((const char*)Bs + (lin ^ ((col & 7) << 4)));
            }
#pragma unroll
            for (int m = 0; m < 4; m++)
#pragma unroll
                for (int n = 0; n < 4; n++)
                    acc[m][n] = __builtin_amdgcn_mfma_f32_16x16x32_bf16(af[m], bg[n], acc[m][n], 0, 0, 0);
        }
    }
#pragma unroll
    for (int m = 0; m < 4; m++) {
#pragma unroll
        for (int r = 0; r < 4; r++) {
            size_t row = (size_t)(m0 + wm + m * 16 + fg * 4 + r);
#pragma unroll
            for (int n = 0; n < 4; n++) {
                size_t idx = row * N + n0 + wn + n * 16 + fr;
                float v = acc[m][n][r];
                if constexpr (EPI == 0) ((float*)Cout)[idx] = v;
                else if constexpr (EPI == 4) ((unsigned short*)Cout)[idx] = f2bfu(0.5f * v * (1.f + erff(v * 0.70710678118f)));
                else ((float*)Cout)[idx] = v + aux[idx];
            }
        }
    }
}

// ---------------- fused projection GEMM: A=nx [4096][1024], Bt = WT5||INPT [9600][1024] ------
__global__ __launch_bounds__(256) void k_gemm_fused(const unsigned short* __restrict__ A, const unsigned short* __restrict__ Bt,
                                                    unsigned short* __restrict__ RB, unsigned short* __restrict__ KB,
                                                    unsigned short* __restrict__ VB, unsigned short* __restrict__ GB,
                                                    float* __restrict__ WF, unsigned short* __restrict__ C2B) {
    __shared__ alignas(16) unsigned short As[128 * 64];
    __shared__ alignas(16) unsigned short Bs[128 * 64];
    const int tid = threadIdx.x;
    const int m0 = blockIdx.y * 128, n0 = blockIdx.x * 128;
    const int wave = tid >> 6, lane = tid & 63;
    const int wm = (wave >> 1) * 64, wn = (wave & 1) * 64;
    const int fr = lane & 15, fg = lane >> 4;
    const int srow = tid >> 3;
    const int ske = (tid & 7) * 8;
    const int K = 1024;

    f32x4 acc[4][4];
#pragma unroll
    for (int m = 0; m < 4; m++)
#pragma unroll
        for (int n = 0; n < 4; n++) acc[m][n] = (f32x4)(0.f);

    u32x4 ra[4], rb[4];
#pragma unroll
    for (int i = 0; i < 4; i++) {
        ra[i] = *(const u32x4*)(A + (size_t)(m0 + srow + 32 * i) * K + ske);
        rb[i] = *(const u32x4*)(Bt + (size_t)(n0 + srow + 32 * i) * K + ske);
    }
    for (int kt = 0; kt < 16; ++kt) {
        __syncthreads();
#pragma unroll
        for (int i = 0; i < 4; i++) {
            int lin = (tid + 256 * i) * 16;
            int sw = lin ^ (((lin >> 7) & 7) << 4);
            *(u32x4*)((char*)As + sw) = ra[i];
            *(u32x4*)((char*)Bs + sw) = rb[i];
        }
        __syncthreads();
        if (kt + 1 < 16) {
#pragma unroll
            for (int i = 0; i < 4; i++) {
                ra[i] = *(const u32x4*)(A + (size_t)(m0 + srow + 32 * i) * K + (kt + 1) * 64 + ske);
                rb[i] = *(const u32x4*)(Bt + (size_t)(n0 + srow + 32 * i) * K + (kt + 1) * 64 + ske);
            }
        }
#pragma unroll
        for (int ks = 0; ks < 2; ++ks) {
            bf16x8 af[4], bg[4];
#pragma unroll
            for (int m = 0; m < 4; m++) {
                int row = wm + m * 16 + fr;
                int lin = row * 128 + ks * 64 + fg * 16;
                af[m] = *(const bf16x8*)((const char*)As + (lin ^ ((row & 7) << 4)));
            }
#pragma unroll
            for (int n = 0; n < 4; n++) {
                int col = wn + n * 16 + fr;
                int lin = col * 128 + ks * 64 + fg * 16;
                bg[n] = *(const bf16x8*)((const char*)Bs + (lin ^ ((col & 7) << 4)));
            }
#pragma unroll
            for (int m = 0; m < 4; m++)
#pragma unroll
                for (int n = 0; n < 4; n++)
                    acc[m][n] = __builtin_amdgcn_mfma_f32_16x16x32_bf16(af[m], bg[n], acc[m][n], 0, 0, 0);
        }
    }
    const int seg = n0 >> 10;  // block-uniform
#pragma unroll
    for (int m = 0; m < 4; m++) {
#pragma unroll
        for (int r = 0; r < 4; r++) {
            size_t row = (size_t)(m0 + wm + m * 16 + fg * 4 + r);
#pragma unroll
            for (int n = 0; n < 4; n++) {
                int gcol = n0 + wn + n * 16 + fr;
                float v = acc[m][n][r];
                if (n0 < 5120) {
                    size_t idx = row * 1024 + (gcol & 1023);
                    if (seg == 0) RB[idx] = f2bfu(v);
                    else if (seg == 1) KB[idx] = f2bfu(v);
                    else if (seg == 2) VB[idx] = f2bfu(v);
                    else if (seg == 3) GB[idx] = f2bfu(siluf(v));
                    else WF[idx] = expf(-expf(v));
                } else {
                    C2B[row * 4480 + (gcol - 5120)] = f2bfu(v);
                }
            }
        }
    }
}

// ---------------- RWKV chunk prep: in-place RT (over RB), KD (over KB), + KDt, QL, d --------
// grid (128 chunks, 8 bh), 256 thr (thread = k). Chunk L=16.
__global__ __launch_bounds__(256) void k_rwkv_prep(unsigned short* __restrict__ RB, unsigned short* __restrict__ KB,
                                                   const float* __restrict__ WF, const float* __restrict__ u,
                                                   unsigned short* __restrict__ KDt, float* __restrict__ QL,
                                                   float* __restrict__ DD) {
    __shared__ float red[16][257];
    __shared__ float red2[16][17];
    const int c = blockIdx.x, bh = blockIdx.y;
    const int b = bh >> 2, h = bh & 3;
    const int k = threadIdx.x;
    const size_t m0 = (size_t)b * T_ + c * 16;
    const int hk = h * 256 + k;
    const float uv = u[hk];
    float Q = 1.f;
    float kd[16];
#pragma unroll
    for (int s = 0; s < 16; s++) {
        size_t off = (m0 + s) * H_ + hk;
        float r = bfu2f(RB[off]);
        float kv = bfu2f(KB[off]);
        float w = WF[off];
        RB[off] = f2bfu(r * Q);              // RT_t = r_t * Qprev
        Q = fmaxf(Q * w, 1e-35f);            // clamp: avoid 1/Q overflow tail
        float kdv = kv / Q;
        kd[s] = kdv;
        KB[off] = f2bfu(kdv);                // KD_s = k_s / Q_s
        red[s][k] = r * uv * kv;             // diag contribution
    }
    QL[((size_t)(b * 128 + c)) * 1024 + hk] = Q;
    size_t kt0 = (((size_t)(b * 128 + c)) * 1024 + hk) * 16;
#pragma unroll
    for (int s = 0; s < 16; s++) KDt[kt0 + s] = f2bfu(kd[s]);
    __syncthreads();
    {
        int s = threadIdx.x >> 4, part = threadIdx.x & 15;
        float ps = 0.f;
#pragma unroll
        for (int j = 0; j < 16; j++) ps += red[s][part * 16 + j];
        red2[s][part] = ps;
    }
    __syncthreads();
    if (threadIdx.x < 16) {
        float dsum = 0.f;
#pragma unroll
        for (int j = 0; j < 16; j++) dsum += red2[threadIdx.x][j];
        DD[((size_t)bh * 128 + c) * 16 + threadIdx.x] = dsum;
    }
}

// ---------------- RWKV chunked scan (MFMA): grid (4 vtiles, 8 bh), 256 thr (4 waves x 16 v) --
__global__ __launch_bounds__(256) void k_rwkv_chunk(const unsigned short* __restrict__ RT, const unsigned short* __restrict__ KD,
                                                    const unsigned short* __restrict__ KDt, const unsigned short* __restrict__ VB,
                                                    const float* __restrict__ QL, const float* __restrict__ DD,
                                                    float* __restrict__ O) {
    __shared__ unsigned short Sb[64][264];   // bf16 shadow of state, [vloc][k], padded
    __shared__ unsigned short VT[64][24];    // V^T tile [vloc][s]
    __shared__ unsigned short Ab[16][24];    // masked A tile [t][s]
    __shared__ float dls[16];
    const int tid = threadIdx.x;
    const int vt = blockIdx.x, bh = blockIdx.y;
    const int b = bh >> 2, h = bh & 3;
    const int wave = tid >> 6, lane = tid & 63;
    const int l16 = lane & 15, lq = lane >> 4;
    const int wv0 = wave * 16;
    const int hk0 = h * 256;
    const int hv = h * 256 + vt * 64;
    const int svt = tid >> 4;                // staging: s index
    const int vl4 = (tid & 15) * 4;          // staging: v base
    for (int i = tid; i < 64 * 264 / 2; i += 256) ((uint32_t*)Sb)[i] = 0;
    f32x4 sreg[16];
#pragma unroll
    for (int kt = 0; kt < 16; kt++) sreg[kt] = (f32x4)(0.f);
    const int aoff = (lq < 2) ? lq * 8 : 0;  // clamped frag offset for K=16-real ops

    for (int c = 0; c < 128; ++c) {
        const size_t m0 = (size_t)b * T_ + c * 16;
        const size_t bc = (size_t)(b * 128 + c);
        __syncthreads();                     // protect VT/dls from previous chunk readers
        {
            ushort4 v4 = *(const ushort4*)(VB + (m0 + svt) * H_ + hv + vl4);
            VT[vl4 + 0][svt] = v4.x; VT[vl4 + 1][svt] = v4.y;
            VT[vl4 + 2][svt] = v4.z; VT[vl4 + 3][svt] = v4.w;
            if (tid < 16) dls[tid] = DD[((size_t)bh * 128 + c) * 16 + tid];
        }
        __syncthreads();
        // ---- A = RT @ KD^T  (K=256) and o_inter = RT @ S_in (bf16 shadow) ----
        const size_t rowA = (m0 + l16) * H_ + hk0;
        bf16x8 rtf[8];
#pragma unroll
        for (int ks = 0; ks < 8; ks++) rtf[ks] = *(const bf16x8*)(RT + rowA + ks * 32 + lq * 8);
        f32x4 Aacc = (f32x4)(0.f);
#pragma unroll
        for (int ks = 0; ks < 8; ks++) {
            bf16x8 kdf = *(const bf16x8*)(KD + rowA + ks * 32 + lq * 8);
            Aacc = __builtin_amdgcn_mfma_f32_16x16x32_bf16(rtf[ks], kdf, Aacc, 0, 0, 0);
        }
        f32x4 oacc = (f32x4)(0.f);
#pragma unroll
        for (int ks = 0; ks < 8; ks++) {
            bf16x8 sbf = *(const bf16x8*)(&Sb[wv0 + l16][ks * 32 + lq * 8]);
            oacc = __builtin_amdgcn_mfma_f32_16x16x32_bf16(rtf[ks], sbf, oacc, 0, 0, 0);
        }
        // ---- mask A (strict lower) + diag d; each wave writes full 16x16 (dup, benign) ----
#pragma unroll
        for (int r = 0; r < 4; r++) {
            int t = lq * 4 + r, s = l16;
            float av = (s < t) ? Aacc[r] : ((s == t) ? dls[t] : 0.f);
            Ab[t][s] = f2bfu(av);
        }
        // ---- o_intra: (A∘mask) @ V, K=16 real (upper half zeroed) ----
        bf16x8 abf_t = *(const bf16x8*)(&Ab[l16][aoff]);
        bf16x8 vtf_t = *(const bf16x8*)(&VT[wv0 + l16][aoff]);
        bf16x8 abf = (lq < 2) ? abf_t : zero8();
        bf16x8 vtf = (lq < 2) ? vtf_t : zero8();
        oacc = __builtin_amdgcn_mfma_f32_16x16x32_bf16(abf, vtf, oacc, 0, 0, 0);
#pragma unroll
        for (int r = 0; r < 4; r++)
            O[(m0 + lq * 4 + r) * H_ + hv + wv0 + l16] = oacc[r];
        // ---- state: S' = QL ∘ (S + KD^T @ V); refresh bf16 shadow ----
#pragma unroll
        for (int kt = 0; kt < 16; kt++) {
            const unsigned short* kp = KDt + (((bc * 1024) + hk0 + kt * 16 + l16) << 4) + aoff;
            bf16x8 kdtf_t = *(const bf16x8*)kp;
            bf16x8 kdtf = (lq < 2) ? kdtf_t : zero8();
            sreg[kt] = __builtin_amdgcn_mfma_f32_16x16x32_bf16(kdtf, vtf, sreg[kt], 0, 0, 0);
            f32x4 ql = *(const f32x4*)(QL + bc * 1024 + hk0 + kt * 16 + lq * 4);
            sreg[kt] *= ql;
            ushort4 pk;
            pk.x = f2bfu(sreg[kt][0]); pk.y = f2bfu(sreg[kt][1]);
            pk.z = f2bfu(sreg[kt][2]); pk.w = f2bfu(sreg[kt][3]);
            *(ushort4*)(&Sb[wv0 + l16][kt * 16 + lq * 4]) = pk;
        }
    }
}

// ---------------- RWKV post: per-head RMS * gn_w * g -> bf16 (in place over g) ----------------
__global__ __launch_bounds__(256) void k_rwkv_post(const float* __restrict__ o, const float* __restrict__ gn_w,
                                                   unsigned short* __restrict__ g_io) {
    int m = blockIdx.x, tid = threadIdx.x;
    int wave = tid >> 6, lane = tid & 63;
    size_t base = (size_t)m * H_ + wave * 256 + lane * 4;
    int col = wave * 256 + lane * 4;
    float4 v = *(const float4*)(o + base);
    float ss = v.x * v.x + v.y * v.y + v.z * v.z + v.w * v.w;
#pragma unroll
    for (int off = 32; off; off >>= 1) ss += __shfl_xor(ss, off);
    float scale = rsqrtf(ss * (1.f / 256.f) + EPS_);
    float4 gn = *(const float4*)(gn_w + col);
    ushort4 gb4 = *(const ushort4*)(g_io + base);
    ushort4 out;
    out.x = f2bfu(v.x * scale * gn.x * bfu2f(gb4.x));
    out.y = f2bfu(v.y * scale * gn.y * bfu2f(gb4.y));
    out.z = f2bfu(v.z * scale * gn.z * bfu2f(gb4.z));
    out.w = f2bfu(v.w * scale * gn.w * bfu2f(gb4.w));
    *(ushort4*)(g_io + base) = out;
}

// ---------------- causal depthwise conv(4) + bias + silu (bf16 in, split out) ----------------
__global__ __launch_bounds__(256) void k_conv(const unsigned short* __restrict__ C2B, const float* __restrict__ conv_w,
                                              const float* __restrict__ conv_b, unsigned short* __restrict__ XB,
                                              float* __restrict__ BCF) {
    int m = blockIdx.y;
    int c = blockIdx.x * 256 + threadIdx.x;  // < 2304
    int b = m >> 11, t = m & 2047;
    float acc = conv_b[c];
#pragma unroll
    for (int i = 0; i < 4; i++) {
        int tt = t - 3 + i;
        if (tt >= 0) acc = fmaf(bfu2f(C2B[((size_t)(b * T_ + tt)) * LD2 + DI + c]), conv_w[c * 4 + i], acc);
    }
    float r = siluf(acc);
    if (c < DI) XB[(size_t)m * DI + c] = f2bfu(r);
    else BCF[(size_t)m * 256 + (c - DI)] = r;
}

// ---------------- Mamba sequential scan (deferred reduction, s-split) ----------------
#define MT 32
__global__ __launch_bounds__(256, 2) void k_mamba_scan(const unsigned short* __restrict__ C2B, const unsigned short* __restrict__ XB,
                                                       const float* __restrict__ BCF,
                                                       const float* __restrict__ dt_bias, const float* __restrict__ A_log,
                                                       unsigned short* __restrict__ Y0, unsigned short* __restrict__ Y1) {
    __shared__ float lB[MT][64], lC[MT][64], lx[MT][16], lda[MT], ldt[MT];
    __shared__ float pst[MT * 272];   // [tt][dloc*17 + li]
    const int tid = threadIdx.x;
    const int d0 = blockIdx.x * 16;
    const int sh = blockIdx.y;
    const int bh = blockIdx.z;
    const int b = bh >> 5, h = bh & 31;
    const int wave = tid >> 6, lane = tid & 63;
    const int dloc = wave * 4 + (lane >> 4);
    const int li = lane & 15;
    const size_t baseM = (size_t)b * T_;
    const float A = -expf(A_log[h]);
    const float dtb = dt_bias[h];
    unsigned short* __restrict__ YP = sh ? Y1 : Y0;
    float hS[4] = {0.f, 0.f, 0.f, 0.f};

    for (int c = 0; c < T_ / MT; ++c) {
        __syncthreads();
        int t0 = c * MT;
#pragma unroll
        for (int it = 0; it < 2; ++it) {
            int idx = (tid + it * 256) * 4;
            int tt = idx >> 6, s = idx & 63;
            const float* src = BCF + (baseM + t0 + tt) * 256 + sh * 64 + s;
            *(float4*)&lB[tt][s] = *(const float4*)(src);
            *(float4*)&lC[tt][s] = *(const float4*)(src + 128);
        }
#pragma unroll
        for (int it = 0; it < 2; ++it) {
            int idx = tid + it * 256;
            int tt = idx >> 4, i = idx & 15;
            lx[tt][i] = bfu2f(XB[(baseM + t0 + tt) * DI + h * 64 + d0 + i]);
        }
        if (tid < MT) {
            float draw = bfu2f(C2B[(baseM + t0 + tid) * LD2 + 4352 + h]) + dtb;
            float ds = draw > 20.f ? draw : log1pf(expf(draw));
            ldt[tid] = ds;
            lda[tid] = expf(A * ds);
        }
        __syncthreads();
#pragma unroll 1
        for (int tt = 0; tt < MT; ++tt) {
            float da = lda[tt];
            float dtx = ldt[tt] * lx[tt][dloc];
            float4 Bv = *(const float4*)&lB[tt][li * 4];
            float4 Cv = *(const float4*)&lC[tt][li * 4];
            hS[0] = fmaf(hS[0], da, dtx * Bv.x);
            hS[1] = fmaf(hS[1], da, dtx * Bv.y);
            hS[2] = fmaf(hS[2], da, dtx * Bv.z);
            hS[3] = fmaf(hS[3], da, dtx * Bv.w);
            float p0 = fmaf(hS[1], Cv.y, hS[0] * Cv.x);
            float p1 = fmaf(hS[3], Cv.w, hS[2] * Cv.z);
            pst[tt * 272 + dloc * 17 + li] = p0 + p1;
        }
        __syncthreads();
        {
            int tt = tid >> 3, dl = tid & 7;
            const float* row0 = &pst[tt * 272 + dl * 17];
            const float* row1 = &pst[tt * 272 + (dl + 8) * 17];
            float s0 = 0.f, s1 = 0.f;
#pragma unroll
            for (int j = 0; j < 16; j++) { s0 += row0[j]; s1 += row1[j]; }
            size_t orow = (baseM + t0 + tt) * DI + h * 64 + d0;
            YP[orow + dl] = f2bfu(s0);
            YP[orow + dl + 8] = f2bfu(s1);
        }
    }
}

// ---------------- Mamba post: (y0+y1 + D*x) * silu(z), RMS(2048) * m_norm_w -> bf16 over y0 ----
__global__ __launch_bounds__(256) void k_mamba_post(unsigned short* __restrict__ y_io, const unsigned short* __restrict__ y1,
                                                    const unsigned short* __restrict__ XB,
                                                    const unsigned short* __restrict__ C2B, const float* __restrict__ D_m,
                                                    const float* __restrict__ mnw) {
    __shared__ float red[4];
    int m = blockIdx.x, tid = threadIdx.x;
    int j0 = tid * 8;
    const float Dv = D_m[j0 >> 6];
    ushort4 ya = *(const ushort4*)(y_io + (size_t)m * DI + j0);
    ushort4 yb = *(const ushort4*)(y_io + (size_t)m * DI + j0 + 4);
    ushort4 wa = *(const ushort4*)(y1 + (size_t)m * DI + j0);
    ushort4 wb = *(const ushort4*)(y1 + (size_t)m * DI + j0 + 4);
    ushort4 xa = *(const ushort4*)(XB + (size_t)m * DI + j0);
    ushort4 xb = *(const ushort4*)(XB + (size_t)m * DI + j0 + 4);
    ushort4 za = *(const ushort4*)(C2B + (size_t)m * LD2 + j0);
    ushort4 zb = *(const ushort4*)(C2B + (size_t)m * LD2 + j0 + 4);
    float yv[8] = {bfu2f(ya.x) + bfu2f(wa.x), bfu2f(ya.y) + bfu2f(wa.y), bfu2f(ya.z) + bfu2f(wa.z), bfu2f(ya.w) + bfu2f(wa.w),
                   bfu2f(yb.x) + bfu2f(wb.x), bfu2f(yb.y) + bfu2f(wb.y), bfu2f(yb.z) + bfu2f(wb.z), bfu2f(yb.w) + bfu2f(wb.w)};
    float xv[8] = {bfu2f(xa.x), bfu2f(xa.y), bfu2f(xa.z), bfu2f(xa.w), bfu2f(xb.x), bfu2f(xb.y), bfu2f(xb.z), bfu2f(xb.w)};
    float zv[8] = {bfu2f(za.x), bfu2f(za.y), bfu2f(za.z), bfu2f(za.w), bfu2f(zb.x), bfu2f(zb.y), bfu2f(zb.z), bfu2f(zb.w)};
    float val[8];
    float ss = 0.f;
#pragma unroll
    for (int i = 0; i < 8; i++) {
        float v = (yv[i] + Dv * xv[i]) * siluf(zv[i]);
        val[i] = v;
        ss += v * v;
    }
#pragma unroll
    for (int off = 32; off; off >>= 1) ss += __shfl_xor(ss, off);
    if ((tid & 63) == 0) red[tid >> 6] = ss;
    __syncthreads();
    float scale = rsqrtf((red[0] + red[1] + red[2] + red[3]) * (1.f / 2048.f) + EPS_);
    ushort4 oa, ob;
    oa.x = f2bfu(val[0] * scale * mnw[j0 + 0]); oa.y = f2bfu(val[1] * scale * mnw[j0 + 1]);
    oa.z = f2bfu(val[2] * scale * mnw[j0 + 2]); oa.w = f2bfu(val[3] * scale * mnw[j0 + 3]);
    ob.x = f2bfu(val[4] * scale * mnw[j0 + 4]); ob.y = f2bfu(val[5] * scale * mnw[j0 + 5]);
    ob.z = f2bfu(val[6] * scale * mnw[j0 + 6]); ob.w = f2bfu(val[7] * scale * mnw[j0 + 7]);
    *(ushort4*)(y_io + (size_t)m * DI + j0) = oa;
    *(ushort4*)(y_io + (size_t)m * DI + j0 + 4) = ob;
}

// ---------------- gate + mix + residual + RMS(ffn_ln) -> x1 f32, nx2 bf16 ----------------
__global__ __launch_bounds__(256) void k_mix(const float* __restrict__ x, const float* __restrict__ o_r,
                                             const float* __restrict__ o_m, const float* __restrict__ gw,
                                             const float* __restrict__ gb, const float* __restrict__ flnw,
                                             float* __restrict__ x1, unsigned short* __restrict__ nx2) {
    __shared__ float red[4];
    int m = blockIdx.x, tid = threadIdx.x;
    size_t base = (size_t)m * H_ + tid * 4;
    float4 orv = *(const float4*)(o_r + base);
    float4 omv = *(const float4*)(o_m + base);
    float4 xv = *(const float4*)(x + base);
    float4 g1 = *(const float4*)(gw + tid * 4);
    float4 g2 = *(const float4*)(gw + 1024 + tid * 4);
    float ps = orv.x * g1.x + orv.y * g1.y + orv.z * g1.z + orv.w * g1.w
             + omv.x * g2.x + omv.y * g2.y + omv.z * g2.z + omv.w * g2.w;
#pragma unroll
    for (int off = 32; off; off >>= 1) ps += __shfl_xor(ps, off);
    if ((tid & 63) == 0) red[tid >> 6] = ps;
    __syncthreads();
    float g = 1.f / (1.f + expf(-(red[0] + red[1] + red[2] + red[3] + gb[0])));
    float4 xo;
    xo.x = xv.x + g * orv.x + (1.f - g) * omv.x;
    xo.y = xv.y + g * orv.y + (1.f - g) * omv.y;
    xo.z = xv.z + g * orv.z + (1.f - g) * omv.z;
    xo.w = xv.w + g * orv.w + (1.f - g) * omv.w;
    *(float4*)(x1 + base) = xo;
    float ss = xo.x * xo.x + xo.y * xo.y + xo.z * xo.z + xo.w * xo.w;
#pragma unroll
    for (int off = 32; off; off >>= 1) ss += __shfl_xor(ss, off);
    __syncthreads();
    if ((tid & 63) == 0) red[tid >> 6] = ss;
    __syncthreads();
    float scale = rsqrtf((red[0] + red[1] + red[2] + red[3]) * (1.f / 1024.f) + EPS_);
    float4 wv = *(const float4*)(flnw + tid * 4);
    ushort4 o;
    o.x = f2bfu(xo.x * scale * wv.x); o.y = f2bfu(xo.y * scale * wv.y);
    o.z = f2bfu(xo.z * scale * wv.z); o.w = f2bfu(xo.w * scale * wv.w);
    *(ushort4*)(nx2 + base) = o;
}

extern "C" void kernel_launch(void* const* d_in, const int* in_sizes, int n_in,
                              void* d_out, int out_size, void* d_ws, size_t ws_size,
                              hipStream_t stream) {
    const float* x = (const float*)d_in[0];
    const float* ln_w = (const float*)d_in[1];
    const float* r_w = (const float*)d_in[2];
    const float* k_w = (const float*)d_in[3];
    const float* v_w = (const float*)d_in[4];
    const float* g_w = (const float*)d_in[5];
    const float* dw_w = (const float*)d_in[6];
    const float* u = (const float*)d_in[7];
    const float* gn_w = (const float*)d_in[8];
    const float* o_w = (const float*)d_in[9];
    const float* in_proj = (const float*)d_in[10];
    const float* conv_w = (const float*)d_in[11];
    const float* conv_b = (const float*)d_in[12];
    const float* dt_bias = (const float*)d_in[13];
    const float* A_log = (const float*)d_in[14];
    const float* D_m = (const float*)d_in[15];
    const float* m_norm_w = (const float*)d_in[16];
    const float* out_proj = (const float*)d_in[17];
    const float* gate_w = (const float*)d_in[18];
    const float* gate_b = (const float*)d_in[19];
    const float* ffn_ln_w = (const float*)d_in[20];
    const float* ffn_w1 = (const float*)d_in[21];
    const float* ffn_w2 = (const float*)d_in[22];
    (void)in_sizes; (void)n_in;

    const size_t NEEDED = 192675840ull;
    if (ws_size < NEEDED) {
        hipMemsetAsync(d_out, 0, (size_t)out_size * 4, stream);
        return;
    }
    char* ws = (char*)d_ws;
    unsigned short* WT5 = (unsigned short*)(ws + 0);            // [5120][1024] bf16
    unsigned short* INPT = (unsigned short*)(ws + 10485760);    // [4480][1024] bf16
    unsigned short* F1T = (unsigned short*)(ws + 0);            // overlay after fused GEMM
    unsigned short* F2T = (unsigned short*)(ws + 10485760);     // overlay
    unsigned short* OWT = (unsigned short*)(ws + 19660800);     // [1024][1024] bf16
    unsigned short* OPT = (unsigned short*)(ws + 21757952);     // [1024][2048] bf16
    unsigned short* NXB = (unsigned short*)(ws + 25952256);     // nx bf16; then KDt; then nx2
    unsigned short* RB = (unsigned short*)(ws + 34340864);      // r -> RT (in place)
    unsigned short* KB = (unsigned short*)(ws + 42729472);      // k -> KD (in place)
    unsigned short* VB = (unsigned short*)(ws + 51118080);      // v bf16
    unsigned short* GB = (unsigned short*)(ws + 59506688);      // silu(g) -> o*gn*g
    float* WF = (float*)(ws + 67895296);                        // decay f32; later Y1
    unsigned short* Y1 = (unsigned short*)(ws + 67895296);      // overlay WF
    float* OM = (float*)(ws + 34340864);                        // overlay RB/KB after chunk scan
    unsigned short* MIDB = (unsigned short*)(ws + 51118080);    // overlay VB/GB/WF at FFN time
    unsigned short* C2B = (unsigned short*)(ws + 84672512);     // [4096][4480] bf16
    unsigned short* XB = (unsigned short*)(ws + 121372672);     // [4096][2048] bf16
    float* BCF = (float*)(ws + 138149888);                      // [4096][256] f32
    float* OBUF = (float*)(ws + 142344192);                     // rwkv o f32; later x1
    float* ORB = (float*)(ws + 159121408);                      // QL+DD (prep/scan); later o_r; later ffn
    unsigned short* YB = (unsigned short*)(ws + 175898624);     // mamba y half0
    unsigned short* KDt = NXB;                                  // [256][1024][16] bf16 = 8 MB
    float* QLb = (float*)(ws + 159121408);                      // [256][1024] f32 = 1 MB
    float* DDb = (float*)(ws + 159121408 + 1048576);            // [8][128][16] f32 = 64 KB

    dim3 blk(256);
    k_rms1024<<<M_, blk, 0, stream>>>(x, ln_w, NXB);
    k_transpose<<<dim3(32, 32), blk, 0, stream>>>(r_w, WT5 + 0ull * 1048576, 1024, 1024, 1024);
    k_transpose<<<dim3(32, 32), blk, 0, stream>>>(k_w, WT5 + 1ull * 1048576, 1024, 1024, 1024);
    k_transpose<<<dim3(32, 32), blk, 0, stream>>>(v_w, WT5 + 2ull * 1048576, 1024, 1024, 1024);
    k_transpose<<<dim3(32, 32), blk, 0, stream>>>(g_w, WT5 + 3ull * 1048576, 1024, 1024, 1024);
    k_transpose<<<dim3(32, 32), blk, 0, stream>>>(dw_w, WT5 + 4ull * 1048576, 1024, 1024, 1024);
    k_transpose<<<dim3(140, 32), blk, 0, stream>>>(in_proj, INPT, 1024, 4384, 4480);
    k_transpose<<<dim3(32, 32), blk, 0, stream>>>(o_w, OWT, 1024, 1024, 1024);
    k_transpose<<<dim3(32, 64), blk, 0, stream>>>(out_proj, OPT, 2048, 1024, 1024);
    // all 6 projections in one GEMM
    k_gemm_fused<<<dim3(75, 32), blk, 0, stream>>>(NXB, WT5, RB, KB, VB, GB, WF, C2B);
    // FFN weight transposes (overlay WT5/INPT region)
    k_transpose<<<dim3(128, 32), blk, 0, stream>>>(ffn_w1, F1T, 1024, 4096, 4096);
    k_transpose<<<dim3(32, 128), blk, 0, stream>>>(ffn_w2, F2T, 4096, 1024, 1024);
    // conv, then rwkv chunked path (prep consumes WF before mamba's Y1 overlays it)
    k_conv<<<dim3(9, M_), blk, 0, stream>>>(C2B, conv_w, conv_b, XB, BCF);
    k_rwkv_prep<<<dim3(128, 8), blk, 0, stream>>>(RB, KB, WF, u, KDt, QLb, DDb);
    k_rwkv_chunk<<<dim3(4, 8), blk, 0, stream>>>(RB, KB, KDt, VB, QLb, DDb, OBUF);
    k_mamba_scan<<<dim3(4, 2, 64), blk, 0, stream>>>(C2B, XB, BCF, dt_bias, A_log, YB, Y1);
    // rwkv output path
    k_rwkv_post<<<M_, blk, 0, stream>>>(OBUF, gn_w, GB);
    k_gemm<0><<<dim3(8, 32), blk, 0, stream>>>(GB, OWT, ORB, nullptr, 4096, 1024, 1024);
    // mamba output path
    k_mamba_post<<<M_, blk, 0, stream>>>(YB, Y1, XB, C2B, D_m, m_norm_w);
    k_gemm<0><<<dim3(8, 32), blk, 0, stream>>>(YB, OPT, OM, nullptr, 4096, 1024, 2048);
    // gate + residual + ffn rms
    k_mix<<<M_, blk, 0, stream>>>(x, ORB, OM, gate_w, gate_b, ffn_ln_w, OBUF, NXB);
    // FFN
    k_gemm<4><<<dim3(32, 32), blk, 0, stream>>>(NXB, F1T, MIDB, nullptr, 4096, 4096, 1024);
    k_gemm<5><<<dim3(8, 32), blk, 0, stream>>>(MIDB, F2T, (float*)d_out, OBUF, 4096, 1024, 4096);
}

// Round 6
// 1202.274 us; speedup vs baseline: 1.5315x; 1.5315x over previous
//
#include <hip/hip_runtime.h>
#include <hip/hip_bf16.h>
#include <stdint.h>

// Sizes (fixed for this problem)
#define B_ 2
#define T_ 2048
#define H_ 1024
#define M_ 4096            // B*T
#define DI 2048
#define DS 128
#define CONVD 2304         // DI + 2*DS
#define LD2 4480           // in_proj out cols: 4384 padded to 128-multiple
#define EPS_ 1e-6f

typedef __bf16 bf16x8 __attribute__((ext_vector_type(8)));
typedef float f32x4 __attribute__((ext_vector_type(4)));
typedef uint32_t u32x4 __attribute__((ext_vector_type(4)));

__device__ __forceinline__ unsigned short f2bfu(float f) {
    union { float f; uint32_t u; } a; a.f = f;
    uint32_t r = a.u + 0x7FFFu + ((a.u >> 16) & 1u);
    return (unsigned short)(r >> 16);
}
__device__ __forceinline__ float bfu2f(unsigned short u) {
    union { uint32_t u; float f; } a; a.u = ((uint32_t)u) << 16; return a.f;
}
__device__ __forceinline__ float siluf(float x) { return x / (1.f + expf(-x)); }

// ---------------- RMS over 1024 cols -> bf16 ----------------
__global__ __launch_bounds__(256) void k_rms1024(const float* __restrict__ in, const float* __restrict__ w,
                                                 unsigned short* __restrict__ out) {
    __shared__ float red[4];
    int m = blockIdx.x, tid = threadIdx.x;
    size_t base = (size_t)m * H_ + tid * 4;
    float4 v = *(const float4*)(in + base);
    float ss = v.x * v.x + v.y * v.y + v.z * v.z + v.w * v.w;
#pragma unroll
    for (int off = 32; off; off >>= 1) ss += __shfl_xor(ss, off);
    if ((tid & 63) == 0) red[tid >> 6] = ss;
    __syncthreads();
    float scale = rsqrtf((red[0] + red[1] + red[2] + red[3]) * (1.f / 1024.f) + EPS_);
    float4 wv = *(const float4*)(w + tid * 4);
    ushort4 o;
    o.x = f2bfu(v.x * wv.x * scale); o.y = f2bfu(v.y * wv.y * scale);
    o.z = f2bfu(v.z * wv.z * scale); o.w = f2bfu(v.w * wv.w * scale);
    *(ushort4*)(out + base) = o;
}

// ---------------- transpose fp32 [K,N] -> bf16 [NP,K] (pad rows with 0) ----------------
__global__ __launch_bounds__(256) void k_transpose(const float* __restrict__ src, unsigned short* __restrict__ dst,
                                                   int K, int N, int NP) {
    __shared__ float t[32][33];
    int n0 = blockIdx.x * 32, k0 = blockIdx.y * 32;
    int tx = threadIdx.x & 31, ty = threadIdx.x >> 5;
#pragma unroll
    for (int i = ty; i < 32; i += 8) {
        int k = k0 + i, n = n0 + tx;
        t[i][tx] = (n < N) ? src[(size_t)k * N + n] : 0.f;
    }
    __syncthreads();
#pragma unroll
    for (int i = ty; i < 32; i += 8) {
        int n = n0 + i, k = k0 + tx;
        if (n < NP) dst[(size_t)n * K + k] = f2bfu(t[tx][i]);
    }
}

// ---------------- bf16 MFMA GEMM: C[M,N] = A[M,K] * Bt[N,K]^T, templated epilogue ----------
// EPI: 0 = f32 store, 4 = gelu->bf16, 5 = f32 store of (v + aux) [residual fusion]
template <int EPI>
__global__ __launch_bounds__(256) void k_gemm(const unsigned short* __restrict__ A, const unsigned short* __restrict__ Bt,
                                              void* __restrict__ Cout, const float* __restrict__ aux,
                                              int M, int N, int K) {
    __shared__ alignas(16) unsigned short As[128 * 64];
    __shared__ alignas(16) unsigned short Bs[128 * 64];
    const int tid = threadIdx.x;
    const int m0 = blockIdx.y * 128, n0 = blockIdx.x * 128;
    const int wave = tid >> 6, lane = tid & 63;
    const int wm = (wave >> 1) * 64, wn = (wave & 1) * 64;
    const int fr = lane & 15, fg = lane >> 4;
    const int srow = tid >> 3;
    const int ske = (tid & 7) * 8;

    f32x4 acc[4][4];
#pragma unroll
    for (int m = 0; m < 4; m++)
#pragma unroll
        for (int n = 0; n < 4; n++) acc[m][n] = (f32x4)(0.f);

    const int nk = K >> 6;
    u32x4 ra[4], rb[4];
#pragma unroll
    for (int i = 0; i < 4; i++) {
        ra[i] = *(const u32x4*)(A + (size_t)(m0 + srow + 32 * i) * K + ske);
        rb[i] = *(const u32x4*)(Bt + (size_t)(n0 + srow + 32 * i) * K + ske);
    }
    for (int kt = 0; kt < nk; ++kt) {
        __syncthreads();
#pragma unroll
        for (int i = 0; i < 4; i++) {
            int lin = (tid + 256 * i) * 16;
            int sw = lin ^ (((lin >> 7) & 7) << 4);
            *(u32x4*)((char*)As + sw) = ra[i];
            *(u32x4*)((char*)Bs + sw) = rb[i];
        }
        __syncthreads();
        if (kt + 1 < nk) {
#pragma unroll
            for (int i = 0; i < 4; i++) {
                ra[i] = *(const u32x4*)(A + (size_t)(m0 + srow + 32 * i) * K + (kt + 1) * 64 + ske);
                rb[i] = *(const u32x4*)(Bt + (size_t)(n0 + srow + 32 * i) * K + (kt + 1) * 64 + ske);
            }
        }
#pragma unroll
        for (int ks = 0; ks < 2; ++ks) {
            bf16x8 af[4], bg[4];
#pragma unroll
            for (int m = 0; m < 4; m++) {
                int row = wm + m * 16 + fr;
                int lin = row * 128 + ks * 64 + fg * 16;
                af[m] = *(const bf16x8*)((const char*)As + (lin ^ ((row & 7) << 4)));
            }
#pragma unroll
            for (int n = 0; n < 4; n++) {
                int col = wn + n * 16 + fr;
                int lin = col * 128 + ks * 64 + fg * 16;
                bg[n] = *(const bf16x8*)((const char*)Bs + (lin ^ ((col & 7) << 4)));
            }
#pragma unroll
            for (int m = 0; m < 4; m++)
#pragma unroll
                for (int n = 0; n < 4; n++)
                    acc[m][n] = __builtin_amdgcn_mfma_f32_16x16x32_bf16(af[m], bg[n], acc[m][n], 0, 0, 0);
        }
    }
#pragma unroll
    for (int m = 0; m < 4; m++) {
#pragma unroll
        for (int r = 0; r < 4; r++) {
            size_t row = (size_t)(m0 + wm + m * 16 + fg * 4 + r);
#pragma unroll
            for (int n = 0; n < 4; n++) {
                size_t idx = row * N + n0 + wn + n * 16 + fr;
                float v = acc[m][n][r];
                if constexpr (EPI == 0) ((float*)Cout)[idx] = v;
                else if constexpr (EPI == 4) ((unsigned short*)Cout)[idx] = f2bfu(0.5f * v * (1.f + erff(v * 0.70710678118f)));
                else ((float*)Cout)[idx] = v + aux[idx];
            }
        }
    }
}

// ---------------- fused projection GEMM: A=nx [4096][1024], Bt = WT5||INPT [9600][1024] ------
__global__ __launch_bounds__(256) void k_gemm_fused(const unsigned short* __restrict__ A, const unsigned short* __restrict__ Bt,
                                                    unsigned short* __restrict__ RB, unsigned short* __restrict__ KB,
                                                    unsigned short* __restrict__ VB, unsigned short* __restrict__ GB,
                                                    float* __restrict__ WF, unsigned short* __restrict__ C2B) {
    __shared__ alignas(16) unsigned short As[128 * 64];
    __shared__ alignas(16) unsigned short Bs[128 * 64];
    const int tid = threadIdx.x;
    const int m0 = blockIdx.y * 128, n0 = blockIdx.x * 128;
    const int wave = tid >> 6, lane = tid & 63;
    const int wm = (wave >> 1) * 64, wn = (wave & 1) * 64;
    const int fr = lane & 15, fg = lane >> 4;
    const int srow = tid >> 3;
    const int ske = (tid & 7) * 8;
    const int K = 1024;

    f32x4 acc[4][4];
#pragma unroll
    for (int m = 0; m < 4; m++)
#pragma unroll
        for (int n = 0; n < 4; n++) acc[m][n] = (f32x4)(0.f);

    u32x4 ra[4], rb[4];
#pragma unroll
    for (int i = 0; i < 4; i++) {
        ra[i] = *(const u32x4*)(A + (size_t)(m0 + srow + 32 * i) * K + ske);
        rb[i] = *(const u32x4*)(Bt + (size_t)(n0 + srow + 32 * i) * K + ske);
    }
    for (int kt = 0; kt < 16; ++kt) {
        __syncthreads();
#pragma unroll
        for (int i = 0; i < 4; i++) {
            int lin = (tid + 256 * i) * 16;
            int sw = lin ^ (((lin >> 7) & 7) << 4);
            *(u32x4*)((char*)As + sw) = ra[i];
            *(u32x4*)((char*)Bs + sw) = rb[i];
        }
        __syncthreads();
        if (kt + 1 < 16) {
#pragma unroll
            for (int i = 0; i < 4; i++) {
                ra[i] = *(const u32x4*)(A + (size_t)(m0 + srow + 32 * i) * K + (kt + 1) * 64 + ske);
                rb[i] = *(const u32x4*)(Bt + (size_t)(n0 + srow + 32 * i) * K + (kt + 1) * 64 + ske);
            }
        }
#pragma unroll
        for (int ks = 0; ks < 2; ++ks) {
            bf16x8 af[4], bg[4];
#pragma unroll
            for (int m = 0; m < 4; m++) {
                int row = wm + m * 16 + fr;
                int lin = row * 128 + ks * 64 + fg * 16;
                af[m] = *(const bf16x8*)((const char*)As + (lin ^ ((row & 7) << 4)));
            }
#pragma unroll
            for (int n = 0; n < 4; n++) {
                int col = wn + n * 16 + fr;
                int lin = col * 128 + ks * 64 + fg * 16;
                bg[n] = *(const bf16x8*)((const char*)Bs + (lin ^ ((col & 7) << 4)));
            }
#pragma unroll
            for (int m = 0; m < 4; m++)
#pragma unroll
                for (int n = 0; n < 4; n++)
                    acc[m][n] = __builtin_amdgcn_mfma_f32_16x16x32_bf16(af[m], bg[n], acc[m][n], 0, 0, 0);
        }
    }
    const int seg = n0 >> 10;  // block-uniform
#pragma unroll
    for (int m = 0; m < 4; m++) {
#pragma unroll
        for (int r = 0; r < 4; r++) {
            size_t row = (size_t)(m0 + wm + m * 16 + fg * 4 + r);
#pragma unroll
            for (int n = 0; n < 4; n++) {
                int gcol = n0 + wn + n * 16 + fr;
                float v = acc[m][n][r];
                if (n0 < 5120) {
                    size_t idx = row * 1024 + (gcol & 1023);
                    if (seg == 0) RB[idx] = f2bfu(v);
                    else if (seg == 1) KB[idx] = f2bfu(v);
                    else if (seg == 2) VB[idx] = f2bfu(v);
                    else if (seg == 3) GB[idx] = f2bfu(siluf(v));
                    else WF[idx] = expf(-expf(v));
                } else {
                    C2B[row * 4480 + (gcol - 5120)] = f2bfu(v);
                }
            }
        }
    }
}

// ---------------- RWKV u-bonus: D[m][h] = sum_k r*u*k (v-independent) ----------------
__global__ __launch_bounds__(256) void k_rwkv_dd(const unsigned short* __restrict__ RB, const unsigned short* __restrict__ KB,
                                                 const float* __restrict__ u, float* __restrict__ DD) {
    int m = blockIdx.x, tid = threadIdx.x;
    int wave = tid >> 6;
    size_t base = (size_t)m * H_ + tid * 4;
    ushort4 r4 = *(const ushort4*)(RB + base);
    ushort4 k4 = *(const ushort4*)(KB + base);
    float4 uv = *(const float4*)(u + tid * 4);
    float s = bfu2f(r4.x) * uv.x * bfu2f(k4.x)
            + bfu2f(r4.y) * uv.y * bfu2f(k4.y)
            + bfu2f(r4.z) * uv.z * bfu2f(k4.z)
            + bfu2f(r4.w) * uv.w * bfu2f(k4.w);
#pragma unroll
    for (int off = 32; off; off >>= 1) s += __shfl_xor(s, off);
    if ((tid & 63) == 0) DD[m * 4 + wave] = s;
}

// ---------------- RWKV sequential scan v3: k-split 4, deferred reduction, no shuffles --------
// grid (32 vb, 4 kh, 8 bh) = 1024 blocks, 256 thr (4 waves). Block: 8 v, 64 k. Lane: 2 k x 1 v.
#define RT 16
__global__ __launch_bounds__(256, 4) void k_rwkv_scan(const unsigned short* __restrict__ RB, const unsigned short* __restrict__ KB,
                                                      const unsigned short* __restrict__ VB, const float* __restrict__ WF,
                                                      float* __restrict__ P0, float* __restrict__ P1,
                                                      float* __restrict__ P2, float* __restrict__ P3) {
    __shared__ float lr[RT][64], lk[RT][64], lw[RT][64];
    __shared__ float lv[RT][8];
    __shared__ float pst[RT * 292];    // [tt][w*72 + kq*9 + vv]
    const int tid = threadIdx.x;
    const int vb = blockIdx.x, kh = blockIdx.y, bh = blockIdx.z;
    const int b = bh >> 2, h = bh & 3;
    const int v0 = vb * 8;
    const int wave = tid >> 6, lane = tid & 63;
    const int kq = lane >> 3, vv = lane & 7;
    const int kloc = wave * 16 + kq * 2;
    const size_t baseM = (size_t)b * T_;
    float* __restrict__ OP = (kh == 0) ? P0 : (kh == 1) ? P1 : (kh == 2) ? P2 : P3;
    float S0 = 0.f, S1 = 0.f;
    const int stt = tid >> 4;          // staging: t index 0..15
    const int sk = (tid & 15) * 4;     // staging: k base 0..60

    for (int c = 0; c < T_ / RT; ++c) {
        __syncthreads();
        int t0 = c * RT;
        {
            size_t rowb = (baseM + t0 + stt) * H_ + h * 256 + kh * 64 + sk;
            ushort4 r4 = *(const ushort4*)(RB + rowb);
            ushort4 k4 = *(const ushort4*)(KB + rowb);
            float4 w4 = *(const float4*)(WF + rowb);
            float4 rf, kf;
            rf.x = bfu2f(r4.x); rf.y = bfu2f(r4.y); rf.z = bfu2f(r4.z); rf.w = bfu2f(r4.w);
            kf.x = bfu2f(k4.x); kf.y = bfu2f(k4.y); kf.z = bfu2f(k4.z); kf.w = bfu2f(k4.w);
            *(float4*)&lr[stt][sk] = rf;
            *(float4*)&lk[stt][sk] = kf;
            *(float4*)&lw[stt][sk] = w4;
        }
        if (tid < RT * 8) {
            int tt = tid >> 3, xx = tid & 7;
            lv[tt][xx] = bfu2f(VB[(baseM + t0 + tt) * H_ + h * 256 + v0 + xx]);
        }
        __syncthreads();
#pragma unroll 1
        for (int tt = 0; tt < RT; ++tt) {
            float vt = lv[tt][vv];
            float2 rr = *(const float2*)&lr[tt][kloc];
            float2 kk = *(const float2*)&lk[tt][kloc];
            float2 ww = *(const float2*)&lw[tt][kloc];
            float p = rr.x * S0;
            p = fmaf(rr.y, S1, p);
            S0 = fmaf(S0, ww.x, kk.x * vt);
            S1 = fmaf(S1, ww.y, kk.y * vt);
            pst[tt * 292 + wave * 72 + kq * 9 + vv] = p;
        }
        __syncthreads();
        if (tid < RT * 8) {
            int tt = tid >> 3, x = tid & 7;
            float s = 0.f;
#pragma unroll
            for (int w = 0; w < 4; w++)
#pragma unroll
                for (int q = 0; q < 8; q++) s += pst[tt * 292 + w * 72 + q * 9 + x];
            OP[(baseM + t0 + tt) * H_ + h * 256 + v0 + x] = s;
        }
    }
}

// ---------------- RWKV post: o = P0+P1+P2+P3 + D*v; per-head RMS * gn_w * g -> bf16 over g ----
__global__ __launch_bounds__(256) void k_rwkv_post(const float* __restrict__ P0, const float* __restrict__ P1,
                                                   const float* __restrict__ P2, const float* __restrict__ P3,
                                                   const unsigned short* __restrict__ VB, const float* __restrict__ DD,
                                                   const float* __restrict__ gn_w, unsigned short* __restrict__ g_io) {
    int m = blockIdx.x, tid = threadIdx.x;
    int wave = tid >> 6, lane = tid & 63;
    size_t base = (size_t)m * H_ + wave * 256 + lane * 4;
    int col = wave * 256 + lane * 4;
    float4 a = *(const float4*)(P0 + base);
    float4 b4 = *(const float4*)(P1 + base);
    float4 c4 = *(const float4*)(P2 + base);
    float4 d4 = *(const float4*)(P3 + base);
    ushort4 vb4 = *(const ushort4*)(VB + base);
    float dd = DD[m * 4 + wave];
    float4 v;
    v.x = a.x + b4.x + c4.x + d4.x + dd * bfu2f(vb4.x);
    v.y = a.y + b4.y + c4.y + d4.y + dd * bfu2f(vb4.y);
    v.z = a.z + b4.z + c4.z + d4.z + dd * bfu2f(vb4.z);
    v.w = a.w + b4.w + c4.w + d4.w + dd * bfu2f(vb4.w);
    float ss = v.x * v.x + v.y * v.y + v.z * v.z + v.w * v.w;
#pragma unroll
    for (int off = 32; off; off >>= 1) ss += __shfl_xor(ss, off);
    float scale = rsqrtf(ss * (1.f / 256.f) + EPS_);
    float4 gn = *(const float4*)(gn_w + col);
    ushort4 gb4 = *(const ushort4*)(g_io + base);
    ushort4 out;
    out.x = f2bfu(v.x * scale * gn.x * bfu2f(gb4.x));
    out.y = f2bfu(v.y * scale * gn.y * bfu2f(gb4.y));
    out.z = f2bfu(v.z * scale * gn.z * bfu2f(gb4.z));
    out.w = f2bfu(v.w * scale * gn.w * bfu2f(gb4.w));
    *(ushort4*)(g_io + base) = out;
}

// ---------------- causal depthwise conv(4) + bias + silu (bf16 in, split out) ----------------
__global__ __launch_bounds__(256) void k_conv(const unsigned short* __restrict__ C2B, const float* __restrict__ conv_w,
                                              const float* __restrict__ conv_b, unsigned short* __restrict__ XB,
                                              float* __restrict__ BCF) {
    int m = blockIdx.y;
    int c = blockIdx.x * 256 + threadIdx.x;  // < 2304
    int b = m >> 11, t = m & 2047;
    float acc = conv_b[c];
#pragma unroll
    for (int i = 0; i < 4; i++) {
        int tt = t - 3 + i;
        if (tt >= 0) acc = fmaf(bfu2f(C2B[((size_t)(b * T_ + tt)) * LD2 + DI + c]), conv_w[c * 4 + i], acc);
    }
    float r = siluf(acc);
    if (c < DI) XB[(size_t)m * DI + c] = f2bfu(r);
    else BCF[(size_t)m * 256 + (c - DI)] = r;
}

// ---------------- Mamba sequential scan (deferred reduction, s-split) ----------------
#define MT 32
__global__ __launch_bounds__(256, 2) void k_mamba_scan(const unsigned short* __restrict__ C2B, const unsigned short* __restrict__ XB,
                                                       const float* __restrict__ BCF,
                                                       const float* __restrict__ dt_bias, const float* __restrict__ A_log,
                                                       unsigned short* __restrict__ Y0, unsigned short* __restrict__ Y1) {
    __shared__ float lB[MT][64], lC[MT][64], lx[MT][16], lda[MT], ldt[MT];
    __shared__ float pst[MT * 272];   // [tt][dloc*17 + li]
    const int tid = threadIdx.x;
    const int d0 = blockIdx.x * 16;
    const int sh = blockIdx.y;
    const int bh = blockIdx.z;
    const int b = bh >> 5, h = bh & 31;
    const int wave = tid >> 6, lane = tid & 63;
    const int dloc = wave * 4 + (lane >> 4);
    const int li = lane & 15;
    const size_t baseM = (size_t)b * T_;
    const float A = -expf(A_log[h]);
    const float dtb = dt_bias[h];
    unsigned short* __restrict__ YP = sh ? Y1 : Y0;
    float hS[4] = {0.f, 0.f, 0.f, 0.f};

    for (int c = 0; c < T_ / MT; ++c) {
        __syncthreads();
        int t0 = c * MT;
#pragma unroll
        for (int it = 0; it < 2; ++it) {
            int idx = (tid + it * 256) * 4;
            int tt = idx >> 6, s = idx & 63;
            const float* src = BCF + (baseM + t0 + tt) * 256 + sh * 64 + s;
            *(float4*)&lB[tt][s] = *(const float4*)(src);
            *(float4*)&lC[tt][s] = *(const float4*)(src + 128);
        }
#pragma unroll
        for (int it = 0; it < 2; ++it) {
            int idx = tid + it * 256;
            int tt = idx >> 4, i = idx & 15;
            lx[tt][i] = bfu2f(XB[(baseM + t0 + tt) * DI + h * 64 + d0 + i]);
        }
        if (tid < MT) {
            float draw = bfu2f(C2B[(baseM + t0 + tid) * LD2 + 4352 + h]) + dtb;
            float ds = draw > 20.f ? draw : log1pf(expf(draw));
            ldt[tid] = ds;
            lda[tid] = expf(A * ds);
        }
        __syncthreads();
#pragma unroll 1
        for (int tt = 0; tt < MT; ++tt) {
            float da = lda[tt];
            float dtx = ldt[tt] * lx[tt][dloc];
            float4 Bv = *(const float4*)&lB[tt][li * 4];
            float4 Cv = *(const float4*)&lC[tt][li * 4];
            hS[0] = fmaf(hS[0], da, dtx * Bv.x);
            hS[1] = fmaf(hS[1], da, dtx * Bv.y);
            hS[2] = fmaf(hS[2], da, dtx * Bv.z);
            hS[3] = fmaf(hS[3], da, dtx * Bv.w);
            float p0 = fmaf(hS[1], Cv.y, hS[0] * Cv.x);
            float p1 = fmaf(hS[3], Cv.w, hS[2] * Cv.z);
            pst[tt * 272 + dloc * 17 + li] = p0 + p1;
        }
        __syncthreads();
        {
            int tt = tid >> 3, dl = tid & 7;
            const float* row0 = &pst[tt * 272 + dl * 17];
            const float* row1 = &pst[tt * 272 + (dl + 8) * 17];
            float s0 = 0.f, s1 = 0.f;
#pragma unroll
            for (int j = 0; j < 16; j++) { s0 += row0[j]; s1 += row1[j]; }
            size_t orow = (baseM + t0 + tt) * DI + h * 64 + d0;
            YP[orow + dl] = f2bfu(s0);
            YP[orow + dl + 8] = f2bfu(s1);
        }
    }
}

// ---------------- Mamba post: (y0+y1 + D*x) * silu(z), RMS(2048) * m_norm_w -> bf16 over y0 ----
__global__ __launch_bounds__(256) void k_mamba_post(unsigned short* __restrict__ y_io, const unsigned short* __restrict__ y1,
                                                    const unsigned short* __restrict__ XB,
                                                    const unsigned short* __restrict__ C2B, const float* __restrict__ D_m,
                                                    const float* __restrict__ mnw) {
    __shared__ float red[4];
    int m = blockIdx.x, tid = threadIdx.x;
    int j0 = tid * 8;
    const float Dv = D_m[j0 >> 6];
    ushort4 ya = *(const ushort4*)(y_io + (size_t)m * DI + j0);
    ushort4 yb = *(const ushort4*)(y_io + (size_t)m * DI + j0 + 4);
    ushort4 wa = *(const ushort4*)(y1 + (size_t)m * DI + j0);
    ushort4 wb = *(const ushort4*)(y1 + (size_t)m * DI + j0 + 4);
    ushort4 xa = *(const ushort4*)(XB + (size_t)m * DI + j0);
    ushort4 xb = *(const ushort4*)(XB + (size_t)m * DI + j0 + 4);
    ushort4 za = *(const ushort4*)(C2B + (size_t)m * LD2 + j0);
    ushort4 zb = *(const ushort4*)(C2B + (size_t)m * LD2 + j0 + 4);
    float yv[8] = {bfu2f(ya.x) + bfu2f(wa.x), bfu2f(ya.y) + bfu2f(wa.y), bfu2f(ya.z) + bfu2f(wa.z), bfu2f(ya.w) + bfu2f(wa.w),
                   bfu2f(yb.x) + bfu2f(wb.x), bfu2f(yb.y) + bfu2f(wb.y), bfu2f(yb.z) + bfu2f(wb.z), bfu2f(yb.w) + bfu2f(wb.w)};
    float xv[8] = {bfu2f(xa.x), bfu2f(xa.y), bfu2f(xa.z), bfu2f(xa.w), bfu2f(xb.x), bfu2f(xb.y), bfu2f(xb.z), bfu2f(xb.w)};
    float zv[8] = {bfu2f(za.x), bfu2f(za.y), bfu2f(za.z), bfu2f(za.w), bfu2f(zb.x), bfu2f(zb.y), bfu2f(zb.z), bfu2f(zb.w)};
    float val[8];
    float ss = 0.f;
#pragma unroll
    for (int i = 0; i < 8; i++) {
        float v = (yv[i] + Dv * xv[i]) * siluf(zv[i]);
        val[i] = v;
        ss += v * v;
    }
#pragma unroll
    for (int off = 32; off; off >>= 1) ss += __shfl_xor(ss, off);
    if ((tid & 63) == 0) red[tid >> 6] = ss;
    __syncthreads();
    float scale = rsqrtf((red[0] + red[1] + red[2] + red[3]) * (1.f / 2048.f) + EPS_);
    ushort4 oa, ob;
    oa.x = f2bfu(val[0] * scale * mnw[j0 + 0]); oa.y = f2bfu(val[1] * scale * mnw[j0 + 1]);
    oa.z = f2bfu(val[2] * scale * mnw[j0 + 2]); oa.w = f2bfu(val[3] * scale * mnw[j0 + 3]);
    ob.x = f2bfu(val[4] * scale * mnw[j0 + 4]); ob.y = f2bfu(val[5] * scale * mnw[j0 + 5]);
    ob.z = f2bfu(val[6] * scale * mnw[j0 + 6]); ob.w = f2bfu(val[7] * scale * mnw[j0 + 7]);
    *(ushort4*)(y_io + (size_t)m * DI + j0) = oa;
    *(ushort4*)(y_io + (size_t)m * DI + j0 + 4) = ob;
}

// ---------------- gate + mix + residual + RMS(ffn_ln) -> x1 f32, nx2 bf16 ----------------
__global__ __launch_bounds__(256) void k_mix(const float* __restrict__ x, const float* __restrict__ o_r,
                                             const float* __restrict__ o_m, const float* __restrict__ gw,
                                             const float* __restrict__ gb, const float* __restrict__ flnw,
                                             float* __restrict__ x1, unsigned short* __restrict__ nx2) {
    __shared__ float red[4];
    int m = blockIdx.x, tid = threadIdx.x;
    size_t base = (size_t)m * H_ + tid * 4;
    float4 orv = *(const float4*)(o_r + base);
    float4 omv = *(const float4*)(o_m + base);
    float4 xv = *(const float4*)(x + base);
    float4 g1 = *(const float4*)(gw + tid * 4);
    float4 g2 = *(const float4*)(gw + 1024 + tid * 4);
    float ps = orv.x * g1.x + orv.y * g1.y + orv.z * g1.z + orv.w * g1.w
             + omv.x * g2.x + omv.y * g2.y + omv.z * g2.z + omv.w * g2.w;
#pragma unroll
    for (int off = 32; off; off >>= 1) ps += __shfl_xor(ps, off);
    if ((tid & 63) == 0) red[tid >> 6] = ps;
    __syncthreads();
    float g = 1.f / (1.f + expf(-(red[0] + red[1] + red[2] + red[3] + gb[0])));
    float4 xo;
    xo.x = xv.x + g * orv.x + (1.f - g) * omv.x;
    xo.y = xv.y + g * orv.y + (1.f - g) * omv.y;
    xo.z = xv.z + g * orv.z + (1.f - g) * omv.z;
    xo.w = xv.w + g * orv.w + (1.f - g) * omv.w;
    *(float4*)(x1 + base) = xo;
    float ss = xo.x * xo.x + xo.y * xo.y + xo.z * xo.z + xo.w * xo.w;
#pragma unroll
    for (int off = 32; off; off >>= 1) ss += __shfl_xor(ss, off);
    __syncthreads();
    if ((tid & 63) == 0) red[tid >> 6] = ss;
    __syncthreads();
    float scale = rsqrtf((red[0] + red[1] + red[2] + red[3]) * (1.f / 1024.f) + EPS_);
    float4 wv = *(const float4*)(flnw + tid * 4);
    ushort4 o;
    o.x = f2bfu(xo.x * scale * wv.x); o.y = f2bfu(xo.y * scale * wv.y);
    o.z = f2bfu(xo.z * scale * wv.z); o.w = f2bfu(xo.w * scale * wv.w);
    *(ushort4*)(nx2 + base) = o;
}

extern "C" void kernel_launch(void* const* d_in, const int* in_sizes, int n_in,
                              void* d_out, int out_size, void* d_ws, size_t ws_size,
                              hipStream_t stream) {
    const float* x = (const float*)d_in[0];
    const float* ln_w = (const float*)d_in[1];
    const float* r_w = (const float*)d_in[2];
    const float* k_w = (const float*)d_in[3];
    const float* v_w = (const float*)d_in[4];
    const float* g_w = (const float*)d_in[5];
    const float* dw_w = (const float*)d_in[6];
    const float* u = (const float*)d_in[7];
    const float* gn_w = (const float*)d_in[8];
    const float* o_w = (const float*)d_in[9];
    const float* in_proj = (const float*)d_in[10];
    const float* conv_w = (const float*)d_in[11];
    const float* conv_b = (const float*)d_in[12];
    const float* dt_bias = (const float*)d_in[13];
    const float* A_log = (const float*)d_in[14];
    const float* D_m = (const float*)d_in[15];
    const float* m_norm_w = (const float*)d_in[16];
    const float* out_proj = (const float*)d_in[17];
    const float* gate_w = (const float*)d_in[18];
    const float* gate_b = (const float*)d_in[19];
    const float* ffn_ln_w = (const float*)d_in[20];
    const float* ffn_w1 = (const float*)d_in[21];
    const float* ffn_w2 = (const float*)d_in[22];
    (void)in_sizes; (void)n_in;

    const size_t NEEDED = 192675840ull;
    if (ws_size < NEEDED) {
        hipMemsetAsync(d_out, 0, (size_t)out_size * 4, stream);
        return;
    }
    char* ws = (char*)d_ws;
    unsigned short* WT5 = (unsigned short*)(ws + 0);            // [5120][1024] bf16
    unsigned short* INPT = (unsigned short*)(ws + 10485760);    // [4480][1024] bf16
    unsigned short* F1T = (unsigned short*)(ws + 0);            // overlay (after rwkv_post)
    unsigned short* F2T = (unsigned short*)(ws + 10485760);     // overlay (after rwkv_post)
    float* P2 = (float*)(ws + 0);                               // rwkv partial kh=2 (over WT5, after fused gemm)
    float* DDp = (float*)(ws + 16777216);                       // [4096][4] f32 (inside old INPT region)
    unsigned short* OWT = (unsigned short*)(ws + 19660800);     // [1024][1024] bf16
    unsigned short* OPT = (unsigned short*)(ws + 21757952);     // [1024][2048] bf16
    unsigned short* NXB = (unsigned short*)(ws + 25952256);     // nx bf16; later nx2
    unsigned short* RB = (unsigned short*)(ws + 34340864);      // r bf16
    unsigned short* KB = (unsigned short*)(ws + 42729472);      // k bf16
    unsigned short* VB = (unsigned short*)(ws + 51118080);      // v bf16
    unsigned short* GB = (unsigned short*)(ws + 59506688);      // silu(g) -> o*gn*g
    float* WF = (float*)(ws + 67895296);                        // decay f32; later Y1
    unsigned short* Y1 = (unsigned short*)(ws + 67895296);      // overlay WF (dead after rwkv_scan)
    float* OM = (float*)(ws + 34340864);                        // overlay RB/KB (dead after rwkv_scan)
    unsigned short* MIDB = (unsigned short*)(ws + 51118080);    // overlay VB/GB/WF at FFN time
    unsigned short* C2B = (unsigned short*)(ws + 84672512);     // [4096][4480] bf16
    unsigned short* XB = (unsigned short*)(ws + 121372672);     // [4096][2048] bf16
    float* BCF = (float*)(ws + 138149888);                      // [4096][256] f32
    float* P0 = (float*)(ws + 142344192);                       // rwkv partial kh=0 (OBUF); later x1
    float* P1 = (float*)(ws + 159121408);                       // rwkv partial kh=1 (ORB); later o_r/ffn
    float* P3 = (float*)(ws + 175898624);                       // rwkv partial kh=3 (YB region, pre-mamba)
    unsigned short* YB = (unsigned short*)(ws + 175898624);     // mamba y half0 (after rwkv_post)
    float* OBUF = P0;
    float* ORB = P1;

    dim3 blk(256);
    k_rms1024<<<M_, blk, 0, stream>>>(x, ln_w, NXB);
    k_transpose<<<dim3(32, 32), blk, 0, stream>>>(r_w, WT5 + 0ull * 1048576, 1024, 1024, 1024);
    k_transpose<<<dim3(32, 32), blk, 0, stream>>>(k_w, WT5 + 1ull * 1048576, 1024, 1024, 1024);
    k_transpose<<<dim3(32, 32), blk, 0, stream>>>(v_w, WT5 + 2ull * 1048576, 1024, 1024, 1024);
    k_transpose<<<dim3(32, 32), blk, 0, stream>>>(g_w, WT5 + 3ull * 1048576, 1024, 1024, 1024);
    k_transpose<<<dim3(32, 32), blk, 0, stream>>>(dw_w, WT5 + 4ull * 1048576, 1024, 1024, 1024);
    k_transpose<<<dim3(140, 32), blk, 0, stream>>>(in_proj, INPT, 1024, 4384, 4480);
    k_transpose<<<dim3(32, 32), blk, 0, stream>>>(o_w, OWT, 1024, 1024, 1024);
    k_transpose<<<dim3(32, 64), blk, 0, stream>>>(out_proj, OPT, 2048, 1024, 1024);
    // all 6 projections in one GEMM
    k_gemm_fused<<<dim3(75, 32), blk, 0, stream>>>(NXB, WT5, RB, KB, VB, GB, WF, C2B);
    // conv (mamba prep) + rwkv u-bonus + scan
    k_conv<<<dim3(9, M_), blk, 0, stream>>>(C2B, conv_w, conv_b, XB, BCF);
    k_rwkv_dd<<<M_, blk, 0, stream>>>(RB, KB, u, DDp);
    k_rwkv_scan<<<dim3(32, 4, 8), blk, 0, stream>>>(RB, KB, VB, WF, P0, P1, P2, P3);
    k_rwkv_post<<<M_, blk, 0, stream>>>(P0, P1, P2, P3, VB, DDp, gn_w, GB);
    // FFN weight transposes AFTER rwkv_post (P2/DD dead)
    k_transpose<<<dim3(128, 32), blk, 0, stream>>>(ffn_w1, F1T, 1024, 4096, 4096);
    k_transpose<<<dim3(32, 128), blk, 0, stream>>>(ffn_w2, F2T, 4096, 1024, 1024);
    // rwkv output GEMM (ORB free after post)
    k_gemm<0><<<dim3(8, 32), blk, 0, stream>>>(GB, OWT, ORB, nullptr, 4096, 1024, 1024);
    // mamba scan (YB region free after post; Y1 over dead WF)
    k_mamba_scan<<<dim3(4, 2, 64), blk, 0, stream>>>(C2B, XB, BCF, dt_bias, A_log, YB, Y1);
    k_mamba_post<<<M_, blk, 0, stream>>>(YB, Y1, XB, C2B, D_m, m_norm_w);
    k_gemm<0><<<dim3(8, 32), blk, 0, stream>>>(YB, OPT, OM, nullptr, 4096, 1024, 2048);
    // gate + residual + ffn rms
    k_mix<<<M_, blk, 0, stream>>>(x, ORB, OM, gate_w, gate_b, ffn_ln_w, OBUF, NXB);
    // FFN
    k_gemm<4><<<dim3(32, 32), blk, 0, stream>>>(NXB, F1T, MIDB, nullptr, 4096, 4096, 1024);
    k_gemm<5><<<dim3(8, 32), blk, 0, stream>>>(MIDB, F2T, (float*)d_out, OBUF, 4096, 1024, 4096);
}

// Round 7
// 1044.223 us; speedup vs baseline: 1.7633x; 1.1514x over previous
//
#include <hip/hip_runtime.h>
#include <hip/hip_bf16.h>
#include <stdint.h>

// Sizes (fixed for this problem)
#define B_ 2
#define T_ 2048
#define H_ 1024
#define M_ 4096            // B*T
#define DI 2048
#define DS 128
#define CONVD 2304         // DI + 2*DS
#define LD2 4480           // in_proj out cols: 4384 padded to 128-multiple
#define EPS_ 1e-6f

typedef __bf16 bf16x8 __attribute__((ext_vector_type(8)));
typedef float f32x4 __attribute__((ext_vector_type(4)));
typedef uint32_t u32x4 __attribute__((ext_vector_type(4)));

__device__ __forceinline__ unsigned short f2bfu(float f) {
    union { float f; uint32_t u; } a; a.f = f;
    uint32_t r = a.u + 0x7FFFu + ((a.u >> 16) & 1u);
    return (unsigned short)(r >> 16);
}
__device__ __forceinline__ float bfu2f(unsigned short u) {
    union { uint32_t u; float f; } a; a.u = ((uint32_t)u) << 16; return a.f;
}
__device__ __forceinline__ float siluf(float x) { return x / (1.f + expf(-x)); }
__device__ __forceinline__ bf16x8 zero8() { bf16x8 r{}; return r; }

// ---------------- RMS over 1024 cols -> bf16 ----------------
__global__ __launch_bounds__(256) void k_rms1024(const float* __restrict__ in, const float* __restrict__ w,
                                                 unsigned short* __restrict__ out) {
    __shared__ float red[4];
    int m = blockIdx.x, tid = threadIdx.x;
    size_t base = (size_t)m * H_ + tid * 4;
    float4 v = *(const float4*)(in + base);
    float ss = v.x * v.x + v.y * v.y + v.z * v.z + v.w * v.w;
#pragma unroll
    for (int off = 32; off; off >>= 1) ss += __shfl_xor(ss, off);
    if ((tid & 63) == 0) red[tid >> 6] = ss;
    __syncthreads();
    float scale = rsqrtf((red[0] + red[1] + red[2] + red[3]) * (1.f / 1024.f) + EPS_);
    float4 wv = *(const float4*)(w + tid * 4);
    ushort4 o;
    o.x = f2bfu(v.x * wv.x * scale); o.y = f2bfu(v.y * wv.y * scale);
    o.z = f2bfu(v.z * wv.z * scale); o.w = f2bfu(v.w * wv.w * scale);
    *(ushort4*)(out + base) = o;
}

// ---------------- transpose fp32 [K,N] -> bf16 [NP,K] (pad rows with 0) ----------------
__global__ __launch_bounds__(256) void k_transpose(const float* __restrict__ src, unsigned short* __restrict__ dst,
                                                   int K, int N, int NP) {
    __shared__ float t[32][33];
    int n0 = blockIdx.x * 32, k0 = blockIdx.y * 32;
    int tx = threadIdx.x & 31, ty = threadIdx.x >> 5;
#pragma unroll
    for (int i = ty; i < 32; i += 8) {
        int k = k0 + i, n = n0 + tx;
        t[i][tx] = (n < N) ? src[(size_t)k * N + n] : 0.f;
    }
    __syncthreads();
#pragma unroll
    for (int i = ty; i < 32; i += 8) {
        int n = n0 + i, k = k0 + tx;
        if (n < NP) dst[(size_t)n * K + k] = f2bfu(t[tx][i]);
    }
}

// ---------------- bf16 MFMA GEMM: C[M,N] = A[M,K] * Bt[N,K]^T, templated epilogue ----------
// EPI: 0 = f32 store, 4 = gelu->bf16, 5 = f32 store of (v + aux) [residual fusion]
template <int EPI>
__global__ __launch_bounds__(256) void k_gemm(const unsigned short* __restrict__ A, const unsigned short* __restrict__ Bt,
                                              void* __restrict__ Cout, const float* __restrict__ aux,
                                              int M, int N, int K) {
    __shared__ alignas(16) unsigned short As[128 * 64];
    __shared__ alignas(16) unsigned short Bs[128 * 64];
    const int tid = threadIdx.x;
    const int m0 = blockIdx.y * 128, n0 = blockIdx.x * 128;
    const int wave = tid >> 6, lane = tid & 63;
    const int wm = (wave >> 1) * 64, wn = (wave & 1) * 64;
    const int fr = lane & 15, fg = lane >> 4;
    const int srow = tid >> 3;
    const int ske = (tid & 7) * 8;

    f32x4 acc[4][4];
#pragma unroll
    for (int m = 0; m < 4; m++)
#pragma unroll
        for (int n = 0; n < 4; n++) acc[m][n] = (f32x4)(0.f);

    const int nk = K >> 6;
    u32x4 ra[4], rb[4];
#pragma unroll
    for (int i = 0; i < 4; i++) {
        ra[i] = *(const u32x4*)(A + (size_t)(m0 + srow + 32 * i) * K + ske);
        rb[i] = *(const u32x4*)(Bt + (size_t)(n0 + srow + 32 * i) * K + ske);
    }
    for (int kt = 0; kt < nk; ++kt) {
        __syncthreads();
#pragma unroll
        for (int i = 0; i < 4; i++) {
            int lin = (tid + 256 * i) * 16;
            int sw = lin ^ (((lin >> 7) & 7) << 4);
            *(u32x4*)((char*)As + sw) = ra[i];
            *(u32x4*)((char*)Bs + sw) = rb[i];
        }
        __syncthreads();
        if (kt + 1 < nk) {
#pragma unroll
            for (int i = 0; i < 4; i++) {
                ra[i] = *(const u32x4*)(A + (size_t)(m0 + srow + 32 * i) * K + (kt + 1) * 64 + ske);
                rb[i] = *(const u32x4*)(Bt + (size_t)(n0 + srow + 32 * i) * K + (kt + 1) * 64 + ske);
            }
        }
#pragma unroll
        for (int ks = 0; ks < 2; ++ks) {
            bf16x8 af[4], bg[4];
#pragma unroll
            for (int m = 0; m < 4; m++) {
                int row = wm + m * 16 + fr;
                int lin = row * 128 + ks * 64 + fg * 16;
                af[m] = *(const bf16x8*)((const char*)As + (lin ^ ((row & 7) << 4)));
            }
#pragma unroll
            for (int n = 0; n < 4; n++) {
                int col = wn + n * 16 + fr;
                int lin = col * 128 + ks * 64 + fg * 16;
                bg[n] = *(const bf16x8*)((const char*)Bs + (lin ^ ((col & 7) << 4)));
            }
#pragma unroll
            for (int m = 0; m < 4; m++)
#pragma unroll
                for (int n = 0; n < 4; n++)
                    acc[m][n] = __builtin_amdgcn_mfma_f32_16x16x32_bf16(af[m], bg[n], acc[m][n], 0, 0, 0);
        }
    }
#pragma unroll
    for (int m = 0; m < 4; m++) {
#pragma unroll
        for (int r = 0; r < 4; r++) {
            size_t row = (size_t)(m0 + wm + m * 16 + fg * 4 + r);
#pragma unroll
            for (int n = 0; n < 4; n++) {
                size_t idx = row * N + n0 + wn + n * 16 + fr;
                float v = acc[m][n][r];
                if constexpr (EPI == 0) ((float*)Cout)[idx] = v;
                else if constexpr (EPI == 4) ((unsigned short*)Cout)[idx] = f2bfu(0.5f * v * (1.f + erff(v * 0.70710678118f)));
                else ((float*)Cout)[idx] = v + aux[idx];
            }
        }
    }
}

// ---------------- fused projection GEMM: A=nx [4096][1024], Bt = WT5||INPT [9600][1024] ------
__global__ __launch_bounds__(256) void k_gemm_fused(const unsigned short* __restrict__ A, const unsigned short* __restrict__ Bt,
                                                    unsigned short* __restrict__ RB, unsigned short* __restrict__ KB,
                                                    unsigned short* __restrict__ VB, unsigned short* __restrict__ GB,
                                                    float* __restrict__ WF, unsigned short* __restrict__ C2B) {
    __shared__ alignas(16) unsigned short As[128 * 64];
    __shared__ alignas(16) unsigned short Bs[128 * 64];
    const int tid = threadIdx.x;
    const int m0 = blockIdx.y * 128, n0 = blockIdx.x * 128;
    const int wave = tid >> 6, lane = tid & 63;
    const int wm = (wave >> 1) * 64, wn = (wave & 1) * 64;
    const int fr = lane & 15, fg = lane >> 4;
    const int srow = tid >> 3;
    const int ske = (tid & 7) * 8;
    const int K = 1024;

    f32x4 acc[4][4];
#pragma unroll
    for (int m = 0; m < 4; m++)
#pragma unroll
        for (int n = 0; n < 4; n++) acc[m][n] = (f32x4)(0.f);

    u32x4 ra[4], rb[4];
#pragma unroll
    for (int i = 0; i < 4; i++) {
        ra[i] = *(const u32x4*)(A + (size_t)(m0 + srow + 32 * i) * K + ske);
        rb[i] = *(const u32x4*)(Bt + (size_t)(n0 + srow + 32 * i) * K + ske);
    }
    for (int kt = 0; kt < 16; ++kt) {
        __syncthreads();
#pragma unroll
        for (int i = 0; i < 4; i++) {
            int lin = (tid + 256 * i) * 16;
            int sw = lin ^ (((lin >> 7) & 7) << 4);
            *(u32x4*)((char*)As + sw) = ra[i];
            *(u32x4*)((char*)Bs + sw) = rb[i];
        }
        __syncthreads();
        if (kt + 1 < 16) {
#pragma unroll
            for (int i = 0; i < 4; i++) {
                ra[i] = *(const u32x4*)(A + (size_t)(m0 + srow + 32 * i) * K + (kt + 1) * 64 + ske);
                rb[i] = *(const u32x4*)(Bt + (size_t)(n0 + srow + 32 * i) * K + (kt + 1) * 64 + ske);
            }
        }
#pragma unroll
        for (int ks = 0; ks < 2; ++ks) {
            bf16x8 af[4], bg[4];
#pragma unroll
            for (int m = 0; m < 4; m++) {
                int row = wm + m * 16 + fr;
                int lin = row * 128 + ks * 64 + fg * 16;
                af[m] = *(const bf16x8*)((const char*)As + (lin ^ ((row & 7) << 4)));
            }
#pragma unroll
            for (int n = 0; n < 4; n++) {
                int col = wn + n * 16 + fr;
                int lin = col * 128 + ks * 64 + fg * 16;
                bg[n] = *(const bf16x8*)((const char*)Bs + (lin ^ ((col & 7) << 4)));
            }
#pragma unroll
            for (int m = 0; m < 4; m++)
#pragma unroll
                for (int n = 0; n < 4; n++)
                    acc[m][n] = __builtin_amdgcn_mfma_f32_16x16x32_bf16(af[m], bg[n], acc[m][n], 0, 0, 0);
        }
    }
    const int seg = n0 >> 10;  // block-uniform
#pragma unroll
    for (int m = 0; m < 4; m++) {
#pragma unroll
        for (int r = 0; r < 4; r++) {
            size_t row = (size_t)(m0 + wm + m * 16 + fg * 4 + r);
#pragma unroll
            for (int n = 0; n < 4; n++) {
                int gcol = n0 + wn + n * 16 + fr;
                float v = acc[m][n][r];
                if (n0 < 5120) {
                    size_t idx = row * 1024 + (gcol & 1023);
                    if (seg == 0) RB[idx] = f2bfu(v);
                    else if (seg == 1) KB[idx] = f2bfu(v);
                    else if (seg == 2) VB[idx] = f2bfu(v);
                    else if (seg == 3) GB[idx] = f2bfu(siluf(v));
                    else WF[idx] = expf(-expf(v));
                } else {
                    C2B[row * 4480 + (gcol - 5120)] = f2bfu(v);
                }
            }
        }
    }
}

// ---------------- RWKV chunk prep (L=16): in-place RT/KD, + KDt, QL(bf16), DD halves --------
__global__ __launch_bounds__(256) void k_rwkv_prep(unsigned short* __restrict__ RB, unsigned short* __restrict__ KB,
                                                   const float* __restrict__ WF, const float* __restrict__ u,
                                                   unsigned short* __restrict__ KDt, unsigned short* __restrict__ QLb,
                                                   float* __restrict__ DDb) {
    __shared__ float red[16][257];
    __shared__ float red2[16][17];
    const int c = blockIdx.x, bh = blockIdx.y;
    const int b = bh >> 2, h = bh & 3;
    const int k = threadIdx.x;
    const size_t m0 = (size_t)b * T_ + c * 16;
    const int hk = h * 256 + k;
    const float uv = u[hk];
    float Q = 1.f;
    float kd[16];
#pragma unroll
    for (int s = 0; s < 16; s++) {
        size_t off = (m0 + s) * H_ + hk;
        float r = bfu2f(RB[off]);
        float kv = bfu2f(KB[off]);
        float w = WF[off];
        RB[off] = f2bfu(r * Q);              // RT_t = r_t * Qprev
        Q = fmaxf(Q * w, 1e-35f);            // clamp: avoid 1/Q overflow tail
        float kdv = kv / Q;
        kd[s] = kdv;
        KB[off] = f2bfu(kdv);                // KD_s = k_s / Q_s
        red[s][k] = r * uv * kv;             // diag contribution
    }
    QLb[((size_t)(b * 128 + c)) * 1024 + hk] = f2bfu(Q);
    size_t kt0 = (((size_t)(b * 128 + c)) * 1024 + hk) * 16;
#pragma unroll
    for (int s = 0; s < 16; s++) KDt[kt0 + s] = f2bfu(kd[s]);
    __syncthreads();
    {
        int s = threadIdx.x >> 4, part = threadIdx.x & 15;
        float ps = 0.f;
#pragma unroll
        for (int j = 0; j < 16; j++) ps += red[s][part * 16 + j];
        red2[s][part] = ps;
    }
    __syncthreads();
    if (threadIdx.x < 32) {
        int s = threadIdx.x & 15, half = threadIdx.x >> 4;
        float d = 0.f;
#pragma unroll
        for (int j = 0; j < 8; j++) d += red2[s][half * 8 + j];
        DDb[(((size_t)bh * 128 + c) * 2 + half) * 16 + s] = d;
    }
}

// ---------------- RWKV carry pass: scalar state over all chunks, store coarse Scc ------------
// grid (64 vgroups of 4, 8 bh), 256 thr (k). Scc[bh][cc][v][k] bf16 for cc=1..15.
__global__ __launch_bounds__(256) void k_rwkv_carry(const unsigned short* __restrict__ KD, const unsigned short* __restrict__ VB,
                                                    const unsigned short* __restrict__ QLb, unsigned short* __restrict__ Scc) {
    __shared__ unsigned short kds[16][256];
    __shared__ float lv[16][4];
    const int vg = blockIdx.x, bh = blockIdx.y;
    const int b = bh >> 2, h = bh & 3;
    const int k = threadIdx.x;
    const int hk = h * 256 + k;
    const size_t baseM = (size_t)b * T_;
    float s0 = 0.f, s1 = 0.f, s2 = 0.f, s3 = 0.f;
    for (int c = 0; c < 128; ++c) {
        size_t m0 = baseM + c * 16;
        if ((c & 7) == 0 && c > 0) {
            int cc = c >> 3;
            size_t sb = ((size_t)(bh * 16 + cc) * 256 + vg * 4) * 256 + k;
            Scc[sb] = f2bfu(s0); Scc[sb + 256] = f2bfu(s1);
            Scc[sb + 512] = f2bfu(s2); Scc[sb + 768] = f2bfu(s3);
        }
        __syncthreads();
#pragma unroll
        for (int it = 0; it < 2; ++it) {
            int i = threadIdx.x + it * 256;   // 512 chunks of 8 ushorts = 16x256
            int row = i >> 5, col8 = (i & 31) * 8;
            *(u32x4*)&kds[row][col8] = *(const u32x4*)(KD + (m0 + row) * H_ + h * 256 + col8);
        }
        if (threadIdx.x < 64) {
            int t = threadIdx.x >> 2, j = threadIdx.x & 3;
            lv[t][j] = bfu2f(VB[(m0 + t) * H_ + h * 256 + vg * 4 + j]);
        }
        __syncthreads();
        float a0 = 0.f, a1 = 0.f, a2 = 0.f, a3 = 0.f;
#pragma unroll
        for (int t = 0; t < 16; t++) {
            float kdv = bfu2f(kds[t][k]);
            a0 = fmaf(kdv, lv[t][0], a0);
            a1 = fmaf(kdv, lv[t][1], a1);
            a2 = fmaf(kdv, lv[t][2], a2);
            a3 = fmaf(kdv, lv[t][3], a3);
        }
        float ql = bfu2f(QLb[((size_t)(b * 128 + c)) * 1024 + hk]);
        s0 = (s0 + a0) * ql; s1 = (s1 + a1) * ql;
        s2 = (s2 + a2) * ql; s3 = (s3 + a3) * ql;
    }
}

// ---------------- RWKV chunked output (MFMA), coarse+k-half parallel ----------------
// grid (4 vt, 16 cc, 16 = bh*2+kh), 256 thr (4 waves x 16 v). 8 fine chunks per block.
__global__ __launch_bounds__(256) void k_rwkv_out(const unsigned short* __restrict__ RT, const unsigned short* __restrict__ KD,
                                                  const unsigned short* __restrict__ KDt, const unsigned short* __restrict__ VB,
                                                  const unsigned short* __restrict__ QLb, const float* __restrict__ DDb,
                                                  const unsigned short* __restrict__ Scc,
                                                  float* __restrict__ P0, float* __restrict__ P1) {
    __shared__ unsigned short Sb[64][136];   // bf16 state shadow [vloc][k-half], rows 272B (16B mult)
    __shared__ unsigned short VT[64][24];    // V^T tile [vloc][s]
    __shared__ unsigned short Ab[16][24];    // masked A tile [t][s]
    __shared__ float dls[16];
    const int tid = threadIdx.x;
    const int vt = blockIdx.x, cc = blockIdx.y;
    const int bh = blockIdx.z >> 1, kh = blockIdx.z & 1;
    const int b = bh >> 2, h = bh & 3;
    const int wave = tid >> 6, lane = tid & 63;
    const int l16 = lane & 15, lq = lane >> 4;
    const int wv0 = wave * 16;
    const int hk0 = h * 256 + kh * 128;
    const int hv = h * 256 + vt * 64;
    const int aoff = (lq < 2) ? lq * 8 : 0;
    float* __restrict__ OP = kh ? P1 : P0;
    f32x4 sreg[8];
    if (cc == 0) {
#pragma unroll
        for (int kt = 0; kt < 8; kt++) sreg[kt] = (f32x4)(0.f);
        for (int i = tid; i < 64 * 136 / 8; i += 256) ((u32x4*)Sb)[i] = (u32x4)(0u);
    } else {
        size_t sbase = ((size_t)(bh * 16 + cc) * 256 + vt * 64);
        for (int i = tid; i < 1024; i += 256) {
            int v = i >> 4, k8 = (i & 15) * 8;
            *(u32x4*)&Sb[v][k8] = *(const u32x4*)(Scc + (sbase + v) * 256 + kh * 128 + k8);
        }
#pragma unroll
        for (int kt = 0; kt < 8; kt++) {
            ushort4 w4 = *(const ushort4*)(Scc + (sbase + wv0 + l16) * 256 + kh * 128 + kt * 16 + lq * 4);
            sreg[kt][0] = bfu2f(w4.x); sreg[kt][1] = bfu2f(w4.y);
            sreg[kt][2] = bfu2f(w4.z); sreg[kt][3] = bfu2f(w4.w);
        }
    }
    __syncthreads();

    for (int fc = 0; fc < 8; ++fc) {
        const int c = cc * 8 + fc;
        const size_t m0 = (size_t)b * T_ + c * 16;
        const size_t bc = (size_t)(b * 128 + c);
        if (fc > 0) __syncthreads();         // protect VT/dls from previous readers
        {
            int st = tid >> 4, v4 = (tid & 15) * 4;
            ushort4 v4v = *(const ushort4*)(VB + (m0 + st) * H_ + hv + v4);
            VT[v4 + 0][st] = v4v.x; VT[v4 + 1][st] = v4v.y;
            VT[v4 + 2][st] = v4v.z; VT[v4 + 3][st] = v4v.w;
            if (tid < 16) dls[tid] = DDb[(((size_t)bh * 128 + c) * 2 + kh) * 16 + tid];
        }
        __syncthreads();
        // ---- A-half = RT @ KD^T (K=128) and o_inter = RT @ Sb ----
        const size_t rowA = (m0 + l16) * H_ + hk0;
        bf16x8 rtf[4];
#pragma unroll
        for (int ks = 0; ks < 4; ks++) rtf[ks] = *(const bf16x8*)(RT + rowA + ks * 32 + lq * 8);
        f32x4 Aacc = (f32x4)(0.f);
#pragma unroll
        for (int ks = 0; ks < 4; ks++) {
            bf16x8 kdf = *(const bf16x8*)(KD + rowA + ks * 32 + lq * 8);
            Aacc = __builtin_amdgcn_mfma_f32_16x16x32_bf16(rtf[ks], kdf, Aacc, 0, 0, 0);
        }
        f32x4 oacc = (f32x4)(0.f);
#pragma unroll
        for (int ks = 0; ks < 4; ks++) {
            bf16x8 sbf = *(const bf16x8*)(&Sb[wv0 + l16][ks * 32 + lq * 8]);
            oacc = __builtin_amdgcn_mfma_f32_16x16x32_bf16(rtf[ks], sbf, oacc, 0, 0, 0);
        }
        // ---- mask (strict lower) + diag-half; all waves write identical values ----
#pragma unroll
        for (int r = 0; r < 4; r++) {
            int t = lq * 4 + r, s = l16;
            float av = (s < t) ? Aacc[r] : ((s == t) ? dls[t] : 0.f);
            Ab[t][s] = f2bfu(av);
        }
        // ---- o_intra: (A∘mask) @ V, K=16 real ----
        bf16x8 abf_t = *(const bf16x8*)(&Ab[l16][aoff]);
        bf16x8 vtf_t = *(const bf16x8*)(&VT[wv0 + l16][aoff]);
        bf16x8 abf = (lq < 2) ? abf_t : zero8();
        bf16x8 vtf = (lq < 2) ? vtf_t : zero8();
        oacc = __builtin_amdgcn_mfma_f32_16x16x32_bf16(abf, vtf, oacc, 0, 0, 0);
#pragma unroll
        for (int r = 0; r < 4; r++)
            OP[(m0 + lq * 4 + r) * H_ + hv + wv0 + l16] = oacc[r];
        // ---- state: S' = QL ∘ (S + KD^T @ V); refresh bf16 shadow ----
#pragma unroll
        for (int kt = 0; kt < 8; kt++) {
            const unsigned short* kp = KDt + (((bc * 1024) + hk0 + kt * 16 + l16) << 4) + aoff;
            bf16x8 kdtf_t = *(const bf16x8*)kp;
            bf16x8 kdtf = (lq < 2) ? kdtf_t : zero8();
            sreg[kt] = __builtin_amdgcn_mfma_f32_16x16x32_bf16(kdtf, vtf, sreg[kt], 0, 0, 0);
            ushort4 q4 = *(const ushort4*)(QLb + bc * 1024 + hk0 + kt * 16 + lq * 4);
            sreg[kt][0] *= bfu2f(q4.x); sreg[kt][1] *= bfu2f(q4.y);
            sreg[kt][2] *= bfu2f(q4.z); sreg[kt][3] *= bfu2f(q4.w);
            ushort4 pk;
            pk.x = f2bfu(sreg[kt][0]); pk.y = f2bfu(sreg[kt][1]);
            pk.z = f2bfu(sreg[kt][2]); pk.w = f2bfu(sreg[kt][3]);
            *(ushort4*)(&Sb[wv0 + l16][kt * 16 + lq * 4]) = pk;
        }
    }
}

// ---------------- RWKV post: o = P0+P1; per-head RMS * gn_w * g -> bf16 (in place over g) ----
__global__ __launch_bounds__(256) void k_rwkv_post(const float* __restrict__ P0, const float* __restrict__ P1,
                                                   const float* __restrict__ gn_w, unsigned short* __restrict__ g_io) {
    int m = blockIdx.x, tid = threadIdx.x;
    int wave = tid >> 6, lane = tid & 63;
    size_t base = (size_t)m * H_ + wave * 256 + lane * 4;
    int col = wave * 256 + lane * 4;
    float4 a = *(const float4*)(P0 + base);
    float4 b4 = *(const float4*)(P1 + base);
    float4 v; v.x = a.x + b4.x; v.y = a.y + b4.y; v.z = a.z + b4.z; v.w = a.w + b4.w;
    float ss = v.x * v.x + v.y * v.y + v.z * v.z + v.w * v.w;
#pragma unroll
    for (int off = 32; off; off >>= 1) ss += __shfl_xor(ss, off);
    float scale = rsqrtf(ss * (1.f / 256.f) + EPS_);
    float4 gn = *(const float4*)(gn_w + col);
    ushort4 gb4 = *(const ushort4*)(g_io + base);
    ushort4 out;
    out.x = f2bfu(v.x * scale * gn.x * bfu2f(gb4.x));
    out.y = f2bfu(v.y * scale * gn.y * bfu2f(gb4.y));
    out.z = f2bfu(v.z * scale * gn.z * bfu2f(gb4.z));
    out.w = f2bfu(v.w * scale * gn.w * bfu2f(gb4.w));
    *(ushort4*)(g_io + base) = out;
}

// ---------------- causal depthwise conv(4) + bias + silu (bf16 in, split out) ----------------
__global__ __launch_bounds__(256) void k_conv(const unsigned short* __restrict__ C2B, const float* __restrict__ conv_w,
                                              const float* __restrict__ conv_b, unsigned short* __restrict__ XB,
                                              float* __restrict__ BCF) {
    int m = blockIdx.y;
    int c = blockIdx.x * 256 + threadIdx.x;  // < 2304
    int b = m >> 11, t = m & 2047;
    float acc = conv_b[c];
#pragma unroll
    for (int i = 0; i < 4; i++) {
        int tt = t - 3 + i;
        if (tt >= 0) acc = fmaf(bfu2f(C2B[((size_t)(b * T_ + tt)) * LD2 + DI + c]), conv_w[c * 4 + i], acc);
    }
    float r = siluf(acc);
    if (c < DI) XB[(size_t)m * DI + c] = f2bfu(r);
    else BCF[(size_t)m * 256 + (c - DI)] = r;
}

// ---------------- Mamba sequential scan (deferred reduction, s-split) ----------------
#define MT 32
__global__ __launch_bounds__(256, 2) void k_mamba_scan(const unsigned short* __restrict__ C2B, const unsigned short* __restrict__ XB,
                                                       const float* __restrict__ BCF,
                                                       const float* __restrict__ dt_bias, const float* __restrict__ A_log,
                                                       unsigned short* __restrict__ Y0, unsigned short* __restrict__ Y1) {
    __shared__ float lB[MT][64], lC[MT][64], lx[MT][16], lda[MT], ldt[MT];
    __shared__ float pst[MT * 272];   // [tt][dloc*17 + li]
    const int tid = threadIdx.x;
    const int d0 = blockIdx.x * 16;
    const int sh = blockIdx.y;
    const int bh = blockIdx.z;
    const int b = bh >> 5, h = bh & 31;
    const int wave = tid >> 6, lane = tid & 63;
    const int dloc = wave * 4 + (lane >> 4);
    const int li = lane & 15;
    const size_t baseM = (size_t)b * T_;
    const float A = -expf(A_log[h]);
    const float dtb = dt_bias[h];
    unsigned short* __restrict__ YP = sh ? Y1 : Y0;
    float hS[4] = {0.f, 0.f, 0.f, 0.f};

    for (int c = 0; c < T_ / MT; ++c) {
        __syncthreads();
        int t0 = c * MT;
#pragma unroll
        for (int it = 0; it < 2; ++it) {
            int idx = (tid + it * 256) * 4;
            int tt = idx >> 6, s = idx & 63;
            const float* src = BCF + (baseM + t0 + tt) * 256 + sh * 64 + s;
            *(float4*)&lB[tt][s] = *(const float4*)(src);
            *(float4*)&lC[tt][s] = *(const float4*)(src + 128);
        }
#pragma unroll
        for (int it = 0; it < 2; ++it) {
            int idx = tid + it * 256;
            int tt = idx >> 4, i = idx & 15;
            lx[tt][i] = bfu2f(XB[(baseM + t0 + tt) * DI + h * 64 + d0 + i]);
        }
        if (tid < MT) {
            float draw = bfu2f(C2B[(baseM + t0 + tid) * LD2 + 4352 + h]) + dtb;
            float ds = draw > 20.f ? draw : log1pf(expf(draw));
            ldt[tid] = ds;
            lda[tid] = expf(A * ds);
        }
        __syncthreads();
#pragma unroll 1
        for (int tt = 0; tt < MT; ++tt) {
            float da = lda[tt];
            float dtx = ldt[tt] * lx[tt][dloc];
            float4 Bv = *(const float4*)&lB[tt][li * 4];
            float4 Cv = *(const float4*)&lC[tt][li * 4];
            hS[0] = fmaf(hS[0], da, dtx * Bv.x);
            hS[1] = fmaf(hS[1], da, dtx * Bv.y);
            hS[2] = fmaf(hS[2], da, dtx * Bv.z);
            hS[3] = fmaf(hS[3], da, dtx * Bv.w);
            float p0 = fmaf(hS[1], Cv.y, hS[0] * Cv.x);
            float p1 = fmaf(hS[3], Cv.w, hS[2] * Cv.z);
            pst[tt * 272 + dloc * 17 + li] = p0 + p1;
        }
        __syncthreads();
        {
            int tt = tid >> 3, dl = tid & 7;
            const float* row0 = &pst[tt * 272 + dl * 17];
            const float* row1 = &pst[tt * 272 + (dl + 8) * 17];
            float s0 = 0.f, s1 = 0.f;
#pragma unroll
            for (int j = 0; j < 16; j++) { s0 += row0[j]; s1 += row1[j]; }
            size_t orow = (baseM + t0 + tt) * DI + h * 64 + d0;
            YP[orow + dl] = f2bfu(s0);
            YP[orow + dl + 8] = f2bfu(s1);
        }
    }
}

// ---------------- Mamba post: (y0+y1 + D*x) * silu(z), RMS(2048) * m_norm_w -> bf16 over y0 ----
__global__ __launch_bounds__(256) void k_mamba_post(unsigned short* __restrict__ y_io, const unsigned short* __restrict__ y1,
                                                    const unsigned short* __restrict__ XB,
                                                    const unsigned short* __restrict__ C2B, const float* __restrict__ D_m,
                                                    const float* __restrict__ mnw) {
    __shared__ float red[4];
    int m = blockIdx.x, tid = threadIdx.x;
    int j0 = tid * 8;
    const float Dv = D_m[j0 >> 6];
    ushort4 ya = *(const ushort4*)(y_io + (size_t)m * DI + j0);
    ushort4 yb = *(const ushort4*)(y_io + (size_t)m * DI + j0 + 4);
    ushort4 wa = *(const ushort4*)(y1 + (size_t)m * DI + j0);
    ushort4 wb = *(const ushort4*)(y1 + (size_t)m * DI + j0 + 4);
    ushort4 xa = *(const ushort4*)(XB + (size_t)m * DI + j0);
    ushort4 xb = *(const ushort4*)(XB + (size_t)m * DI + j0 + 4);
    ushort4 za = *(const ushort4*)(C2B + (size_t)m * LD2 + j0);
    ushort4 zb = *(const ushort4*)(C2B + (size_t)m * LD2 + j0 + 4);
    float yv[8] = {bfu2f(ya.x) + bfu2f(wa.x), bfu2f(ya.y) + bfu2f(wa.y), bfu2f(ya.z) + bfu2f(wa.z), bfu2f(ya.w) + bfu2f(wa.w),
                   bfu2f(yb.x) + bfu2f(wb.x), bfu2f(yb.y) + bfu2f(wb.y), bfu2f(yb.z) + bfu2f(wb.z), bfu2f(yb.w) + bfu2f(wb.w)};
    float xv[8] = {bfu2f(xa.x), bfu2f(xa.y), bfu2f(xa.z), bfu2f(xa.w), bfu2f(xb.x), bfu2f(xb.y), bfu2f(xb.z), bfu2f(xb.w)};
    float zv[8] = {bfu2f(za.x), bfu2f(za.y), bfu2f(za.z), bfu2f(za.w), bfu2f(zb.x), bfu2f(zb.y), bfu2f(zb.z), bfu2f(zb.w)};
    float val[8];
    float ss = 0.f;
#pragma unroll
    for (int i = 0; i < 8; i++) {
        float v = (yv[i] + Dv * xv[i]) * siluf(zv[i]);
        val[i] = v;
        ss += v * v;
    }
#pragma unroll
    for (int off = 32; off; off >>= 1) ss += __shfl_xor(ss, off);
    if ((tid & 63) == 0) red[tid >> 6] = ss;
    __syncthreads();
    float scale = rsqrtf((red[0] + red[1] + red[2] + red[3]) * (1.f / 2048.f) + EPS_);
    ushort4 oa, ob;
    oa.x = f2bfu(val[0] * scale * mnw[j0 + 0]); oa.y = f2bfu(val[1] * scale * mnw[j0 + 1]);
    oa.z = f2bfu(val[2] * scale * mnw[j0 + 2]); oa.w = f2bfu(val[3] * scale * mnw[j0 + 3]);
    ob.x = f2bfu(val[4] * scale * mnw[j0 + 4]); ob.y = f2bfu(val[5] * scale * mnw[j0 + 5]);
    ob.z = f2bfu(val[6] * scale * mnw[j0 + 6]); ob.w = f2bfu(val[7] * scale * mnw[j0 + 7]);
    *(ushort4*)(y_io + (size_t)m * DI + j0) = oa;
    *(ushort4*)(y_io + (size_t)m * DI + j0 + 4) = ob;
}

// ---------------- gate + mix + residual + RMS(ffn_ln) -> x1 f32, nx2 bf16 ----------------
__global__ __launch_bounds__(256) void k_mix(const float* __restrict__ x, const float* __restrict__ o_r,
                                             const float* __restrict__ o_m, const float* __restrict__ gw,
                                             const float* __restrict__ gb, const float* __restrict__ flnw,
                                             float* __restrict__ x1, unsigned short* __restrict__ nx2) {
    __shared__ float red[4];
    int m = blockIdx.x, tid = threadIdx.x;
    size_t base = (size_t)m * H_ + tid * 4;
    float4 orv = *(const float4*)(o_r + base);
    float4 omv = *(const float4*)(o_m + base);
    float4 xv = *(const float4*)(x + base);
    float4 g1 = *(const float4*)(gw + tid * 4);
    float4 g2 = *(const float4*)(gw + 1024 + tid * 4);
    float ps = orv.x * g1.x + orv.y * g1.y + orv.z * g1.z + orv.w * g1.w
             + omv.x * g2.x + omv.y * g2.y + omv.z * g2.z + omv.w * g2.w;
#pragma unroll
    for (int off = 32; off; off >>= 1) ps += __shfl_xor(ps, off);
    if ((tid & 63) == 0) red[tid >> 6] = ps;
    __syncthreads();
    float g = 1.f / (1.f + expf(-(red[0] + red[1] + red[2] + red[3] + gb[0])));
    float4 xo;
    xo.x = xv.x + g * orv.x + (1.f - g) * omv.x;
    xo.y = xv.y + g * orv.y + (1.f - g) * omv.y;
    xo.z = xv.z + g * orv.z + (1.f - g) * omv.z;
    xo.w = xv.w + g * orv.w + (1.f - g) * omv.w;
    *(float4*)(x1 + base) = xo;
    float ss = xo.x * xo.x + xo.y * xo.y + xo.z * xo.z + xo.w * xo.w;
#pragma unroll
    for (int off = 32; off; off >>= 1) ss += __shfl_xor(ss, off);
    __syncthreads();
    if ((tid & 63) == 0) red[tid >> 6] = ss;
    __syncthreads();
    float scale = rsqrtf((red[0] + red[1] + red[2] + red[3]) * (1.f / 1024.f) + EPS_);
    float4 wv = *(const float4*)(flnw + tid * 4);
    ushort4 o;
    o.x = f2bfu(xo.x * scale * wv.x); o.y = f2bfu(xo.y * scale * wv.y);
    o.z = f2bfu(xo.z * scale * wv.z); o.w = f2bfu(xo.w * scale * wv.w);
    *(ushort4*)(nx2 + base) = o;
}

extern "C" void kernel_launch(void* const* d_in, const int* in_sizes, int n_in,
                              void* d_out, int out_size, void* d_ws, size_t ws_size,
                              hipStream_t stream) {
    const float* x = (const float*)d_in[0];
    const float* ln_w = (const float*)d_in[1];
    const float* r_w = (const float*)d_in[2];
    const float* k_w = (const float*)d_in[3];
    const float* v_w = (const float*)d_in[4];
    const float* g_w = (const float*)d_in[5];
    const float* dw_w = (const float*)d_in[6];
    const float* u = (const float*)d_in[7];
    const float* gn_w = (const float*)d_in[8];
    const float* o_w = (const float*)d_in[9];
    const float* in_proj = (const float*)d_in[10];
    const float* conv_w = (const float*)d_in[11];
    const float* conv_b = (const float*)d_in[12];
    const float* dt_bias = (const float*)d_in[13];
    const float* A_log = (const float*)d_in[14];
    const float* D_m = (const float*)d_in[15];
    const float* m_norm_w = (const float*)d_in[16];
    const float* out_proj = (const float*)d_in[17];
    const float* gate_w = (const float*)d_in[18];
    const float* gate_b = (const float*)d_in[19];
    const float* ffn_ln_w = (const float*)d_in[20];
    const float* ffn_w1 = (const float*)d_in[21];
    const float* ffn_w2 = (const float*)d_in[22];
    (void)in_sizes; (void)n_in;

    const size_t NEEDED = 192675840ull;
    if (ws_size < NEEDED) {
        hipMemsetAsync(d_out, 0, (size_t)out_size * 4, stream);
        return;
    }
    char* ws = (char*)d_ws;
    unsigned short* WT5 = (unsigned short*)(ws + 0);            // [5120][1024] bf16 (phase 1)
    unsigned short* INPT = (unsigned short*)(ws + 10485760);    // [4480][1024] bf16 (phase 1)
    unsigned short* QLb = (unsigned short*)(ws + 0);            // rwkv: [256][1024] bf16 = 512K
    float* DDb = (float*)(ws + 524288);                         // rwkv: [8][128][2][16] f32 = 128K
    unsigned short* SCC = (unsigned short*)(ws + 1048576);      // rwkv: [8][16][256][256] bf16 = 16.8M (ends 17825792)
    unsigned short* F1T = (unsigned short*)(ws + 0);            // FFN overlay (after rwkv_out)
    unsigned short* F2T = (unsigned short*)(ws + 10485760);     // FFN overlay (ends 18874368)
    unsigned short* OWT = (unsigned short*)(ws + 19660800);     // [1024][1024] bf16 (never overwritten)
    unsigned short* OPT = (unsigned short*)(ws + 21757952);     // [1024][2048] bf16 (never overwritten)
    unsigned short* NXB = (unsigned short*)(ws + 25952256);     // nx bf16; then KDt; then nx2
    unsigned short* KDt = NXB;                                  // [256][1024][16] bf16 = 8M
    unsigned short* RB = (unsigned short*)(ws + 34340864);      // r -> RT in place
    unsigned short* KB = (unsigned short*)(ws + 42729472);      // k -> KD in place
    unsigned short* VB = (unsigned short*)(ws + 51118080);      // v bf16
    unsigned short* GB = (unsigned short*)(ws + 59506688);      // silu(g) -> o*gn*g
    float* WF = (float*)(ws + 67895296);                        // decay f32; later Y1
    unsigned short* Y1 = (unsigned short*)(ws + 67895296);      // overlay WF (dead after prep)
    float* OM = (float*)(ws + 34340864);                        // overlay RB/KB (dead after rwkv_out)
    unsigned short* MIDB = (unsigned short*)(ws + 51118080);    // overlay VB/GB/WF at FFN time
    unsigned short* C2B = (unsigned short*)(ws + 84672512);     // [4096][4480] bf16
    unsigned short* XB = (unsigned short*)(ws + 121372672);     // [4096][2048] bf16
    float* BCF = (float*)(ws + 138149888);                      // [4096][256] f32
    float* P0 = (float*)(ws + 142344192);                       // rwkv partial kh=0; later x1
    float* P1 = (float*)(ws + 159121408);                       // rwkv partial kh=1; later o_r/ffn out
    unsigned short* YB = (unsigned short*)(ws + 175898624);     // mamba y half0

    dim3 blk(256);
    k_rms1024<<<M_, blk, 0, stream>>>(x, ln_w, NXB);
    k_transpose<<<dim3(32, 32), blk, 0, stream>>>(r_w, WT5 + 0ull * 1048576, 1024, 1024, 1024);
    k_transpose<<<dim3(32, 32), blk, 0, stream>>>(k_w, WT5 + 1ull * 1048576, 1024, 1024, 1024);
    k_transpose<<<dim3(32, 32), blk, 0, stream>>>(v_w, WT5 + 2ull * 1048576, 1024, 1024, 1024);
    k_transpose<<<dim3(32, 32), blk, 0, stream>>>(g_w, WT5 + 3ull * 1048576, 1024, 1024, 1024);
    k_transpose<<<dim3(32, 32), blk, 0, stream>>>(dw_w, WT5 + 4ull * 1048576, 1024, 1024, 1024);
    k_transpose<<<dim3(140, 32), blk, 0, stream>>>(in_proj, INPT, 1024, 4384, 4480);
    k_transpose<<<dim3(32, 32), blk, 0, stream>>>(o_w, OWT, 1024, 1024, 1024);
    k_transpose<<<dim3(32, 64), blk, 0, stream>>>(out_proj, OPT, 2048, 1024, 1024);
    // all 6 projections in one GEMM
    k_gemm_fused<<<dim3(75, 32), blk, 0, stream>>>(NXB, WT5, RB, KB, VB, GB, WF, C2B);
    // conv (mamba prep)
    k_conv<<<dim3(9, M_), blk, 0, stream>>>(C2B, conv_w, conv_b, XB, BCF);
    // rwkv: prep -> carry -> chunked MFMA out -> post
    k_rwkv_prep<<<dim3(128, 8), blk, 0, stream>>>(RB, KB, WF, u, KDt, QLb, DDb);
    k_rwkv_carry<<<dim3(64, 8), blk, 0, stream>>>(KB, VB, QLb, SCC);
    k_rwkv_out<<<dim3(4, 16, 16), blk, 0, stream>>>(RB, KB, KDt, VB, QLb, DDb, SCC, P0, P1);
    k_rwkv_post<<<M_, blk, 0, stream>>>(P0, P1, gn_w, GB);
    // FFN weight transposes AFTER rwkv_out (QLb/SCC region dead)
    k_transpose<<<dim3(128, 32), blk, 0, stream>>>(ffn_w1, F1T, 1024, 4096, 4096);
    k_transpose<<<dim3(32, 128), blk, 0, stream>>>(ffn_w2, F2T, 4096, 1024, 1024);
    // mamba (Y1 over dead WF; YB region free)
    k_mamba_scan<<<dim3(4, 2, 64), blk, 0, stream>>>(C2B, XB, BCF, dt_bias, A_log, YB, Y1);
    k_mamba_post<<<M_, blk, 0, stream>>>(YB, Y1, XB, C2B, D_m, m_norm_w);
    // output GEMMs
    k_gemm<0><<<dim3(8, 32), blk, 0, stream>>>(GB, OWT, P1, nullptr, 4096, 1024, 1024);
    k_gemm<0><<<dim3(8, 32), blk, 0, stream>>>(YB, OPT, OM, nullptr, 4096, 1024, 2048);
    // gate + residual + ffn rms (x1 over P0, nx2 over NXB)
    k_mix<<<M_, blk, 0, stream>>>(x, P1, OM, gate_w, gate_b, ffn_ln_w, P0, NXB);
    // FFN
    k_gemm<4><<<dim3(32, 32), blk, 0, stream>>>(NXB, F1T, MIDB, nullptr, 4096, 4096, 1024);
    k_gemm<5><<<dim3(8, 32), blk, 0, stream>>>(MIDB, F2T, (float*)d_out, P0, 4096, 1024, 4096);
}